// Round 1
// baseline (2997.380 us; speedup 1.0000x reference)
//
#include <hip/hip_runtime.h>
#include <math.h>

// ---------------- avg pool 2x2 ----------------
__global__ void pool_kernel(const float* __restrict__ x, float* __restrict__ y, int total) {
    int idx = blockIdx.x * blockDim.x + threadIdx.x;
    if (idx >= total) return;              // total = 16*384*32*32
    int j  = idx & 31;
    int i  = (idx >> 5) & 31;
    int bc = idx >> 10;                    // b*384 + c
    const float* src = x + (size_t)bc * 4096 + (size_t)(i * 2) * 64 + j * 2;
    y[idx] = 0.25f * (src[0] + src[1] + src[64] + src[65]);
}

// ---------------- tiled fp32 GEMM: Y[b] = act(W @ X[b] + bias) ----------------
// W: [M,K] row-major, X: [K,N] per batch (stride xbs), Y: [M,N] per batch (stride ybs)
// M%64==0, N%64==0, K%16==0 (guaranteed by problem dims)
template<int RELU>
__global__ __launch_bounds__(256) void gemm_kernel(
    const float* __restrict__ W, const float* __restrict__ bias,
    const float* __restrict__ X, float* __restrict__ Y,
    int M, int N, int K, long xbs, long ybs)
{
    __shared__ float Ws[16][68];   // [k][m] transposed; 68 keeps rows 16B-aligned
    __shared__ float Xs[16][68];   // [k][n]
    const int tid = threadIdx.x;
    const int tx = tid & 15, ty = tid >> 4;
    const int n0 = blockIdx.x * 64;
    const int m0 = blockIdx.y * 64;
    const float* Xb = X + (size_t)blockIdx.z * xbs;
    float* Yb = Y + (size_t)blockIdx.z * ybs;

    float acc[4][4] = {};
    const int wm = tid >> 2;          // 0..63  (row within W tile)
    const int wk = (tid & 3) * 4;     // 0,4,8,12
    const int xr = tid >> 4;          // 0..15  (k-row within X tile)
    const int xc = (tid & 15) * 4;    // 0..60

    for (int k0 = 0; k0 < K; k0 += 16) {
        float4 w4 = *(const float4*)&W[(size_t)(m0 + wm) * K + k0 + wk];
        float4 x4 = *(const float4*)&Xb[(size_t)(k0 + xr) * N + n0 + xc];
        Ws[wk + 0][wm] = w4.x;
        Ws[wk + 1][wm] = w4.y;
        Ws[wk + 2][wm] = w4.z;
        Ws[wk + 3][wm] = w4.w;
        *(float4*)&Xs[xr][xc] = x4;
        __syncthreads();
        #pragma unroll
        for (int kk = 0; kk < 16; kk++) {
            float a[4], bx[4];
            *(float4*)a  = *(const float4*)&Ws[kk][ty * 4];
            *(float4*)bx = *(const float4*)&Xs[kk][tx * 4];
            #pragma unroll
            for (int i = 0; i < 4; i++)
                #pragma unroll
                for (int j = 0; j < 4; j++)
                    acc[i][j] += a[i] * bx[j];
        }
        __syncthreads();
    }
    #pragma unroll
    for (int i = 0; i < 4; i++) {
        int m = m0 + ty * 4 + i;
        float bv = bias[m];
        float r[4];
        #pragma unroll
        for (int j = 0; j < 4; j++) {
            r[j] = acc[i][j] + bv;
            if (RELU) r[j] = fmaxf(r[j], 0.0f);
        }
        *(float4*)&Yb[(size_t)m * N + n0 + tx * 4] = *(float4*)r;
    }
}

// ---------------- dustbin: Z row 64 = dw2[1,128] @ h_rows[1024..1151] + db2 ----------------
__global__ void dust_kernel(const float* __restrict__ w, const float* __restrict__ bias,
                            const float* __restrict__ h, float* __restrict__ Z, int N)
{
    int n = blockIdx.x * 256 + threadIdx.x;
    int b = blockIdx.y;
    const float* hb = h + (size_t)b * 1152 * N + (size_t)1024 * N;
    float s = bias[0];
    #pragma unroll 4
    for (int c = 0; c < 128; c++) s += w[c] * hb[(size_t)c * N + n];
    Z[(size_t)b * 65 * N + (size_t)64 * N + n] = s;
}

// ---------------- Sinkhorn (3 iters) + row-normalized P ----------------
// one block per batch, 1024 threads; Z: [65,N] per batch; P out: [64,N] per batch
__global__ __launch_bounds__(1024) void sinkhorn_kernel(const float* __restrict__ Z,
                                                        float* __restrict__ P, int N)
{
    __shared__ float v[4096];
    __shared__ float u[65];
    __shared__ float rs[64];
    const int tid = threadIdx.x;
    const int b = blockIdx.x;
    const float* Zb = Z + (size_t)b * 65 * N;
    float* Pb = P + (size_t)b * 64 * N;
    const float log_mu = -logf(65.0f);
    const float log_nu = -logf((float)N);
    for (int n = tid; n < N; n += 1024) v[n] = 0.0f;
    __syncthreads();
    const int wave = tid >> 6, lane = tid & 63;
    for (int it = 0; it < 3; it++) {
        // u = log_mu - LSE_n(Z + v): one row per wave round-robin
        for (int k = wave; k < 65; k += 16) {
            const float* Zr = Zb + (size_t)k * N;
            float m = -INFINITY, s = 0.0f;
            for (int n = lane; n < N; n += 64) {
                float t = Zr[n] + v[n];
                if (t > m) { s = s * expf(m - t) + 1.0f; m = t; }
                else       { s += expf(t - m); }
            }
            #pragma unroll
            for (int off = 32; off >= 1; off >>= 1) {
                float m2 = __shfl_xor(m, off);
                float s2 = __shfl_xor(s, off);
                float M = fmaxf(m, m2);
                s = s * expf(m - M) + s2 * expf(m2 - M);
                m = M;
            }
            if (lane == 0) u[k] = log_mu - (m + logf(s));
        }
        __syncthreads();
        // v = log_nu - LSE_k(Z + u): one column per thread
        for (int n = tid; n < N; n += 1024) {
            float m = -INFINITY, s = 0.0f;
            for (int k = 0; k < 65; k++) {
                float t = Zb[(size_t)k * N + n] + u[k];
                if (t > m) { s = s * expf(m - t) + 1.0f; m = t; }
                else       { s += expf(t - m); }
            }
            v[n] = log_nu - (m + logf(s));
        }
        __syncthreads();
    }
    // row sums of p (rows 0..63), then write normalized P
    for (int k = wave; k < 64; k += 16) {
        const float* Zr = Zb + (size_t)k * N;
        float uk = u[k];
        float s = 0.0f;
        for (int n = lane; n < N; n += 64) s += expf(Zr[n] + uk + v[n]);
        #pragma unroll
        for (int off = 32; off >= 1; off >>= 1) s += __shfl_xor(s, off);
        if (lane == 0) rs[k] = 1.0f / (s + 1e-8f);
    }
    __syncthreads();
    for (int n = tid; n < N; n += 1024) {
        #pragma unroll 4
        for (int k = 0; k < 64; k++) {
            Pb[(size_t)k * N + n] = expf(Zb[(size_t)k * N + n] + u[k] + v[n]) * rs[k];
        }
    }
}

// ---------------- desc: out[c,k] = sum_n feat[c,n]*P[k,n]; column-normalize; write/accumulate ----------------
// grid: (16 k-groups of 4, chunk batches); block 256 (4 waves)
__global__ __launch_bounds__(256) void desc_kernel(const float* __restrict__ feat,
        const float* __restrict__ P, float* __restrict__ desc, int N, int batch0, int add)
{
    __shared__ float outt[128][4];
    const int b  = blockIdx.y;
    const int kg = blockIdx.x * 4;
    const float* fb = feat + (size_t)b * 128 * N;
    const float* Pb = P + (size_t)b * 64 * N + (size_t)kg * N;
    const int wave = threadIdx.x >> 6, lane = threadIdx.x & 63;
    for (int c = wave; c < 128; c += 4) {
        float a0 = 0, a1 = 0, a2 = 0, a3 = 0;
        const float* fr = fb + (size_t)c * N;
        for (int n = lane; n < N; n += 64) {
            float f = fr[n];
            a0 += f * Pb[n];
            a1 += f * Pb[(size_t)N + n];
            a2 += f * Pb[(size_t)2 * N + n];
            a3 += f * Pb[(size_t)3 * N + n];
        }
        #pragma unroll
        for (int off = 32; off >= 1; off >>= 1) {
            a0 += __shfl_xor(a0, off); a1 += __shfl_xor(a1, off);
            a2 += __shfl_xor(a2, off); a3 += __shfl_xor(a3, off);
        }
        if (lane == 0) { outt[c][0] = a0; outt[c][1] = a1; outt[c][2] = a2; outt[c][3] = a3; }
    }
    __syncthreads();
    // wave j normalizes column j over c (128 values)
    {
        int j = wave;  // 0..3
        float s = 0;
        for (int c = lane; c < 128; c += 64) { float t = outt[c][j]; s += t * t; }
        #pragma unroll
        for (int off = 32; off >= 1; off >>= 1) s += __shfl_xor(s, off);
        float inv = 1.0f / fmaxf(sqrtf(s), 1e-12f);
        float* d = desc + (size_t)(batch0 + b) * 8192;
        for (int c = lane; c < 128; c += 64) {
            float val = outt[c][j] * inv;
            int idx = c * 64 + kg + j;
            if (add) d[idx] += val; else d[idx] = val;
        }
    }
}

// ---------------- final: g = mean(d0,d1); g /= ||g|| ----------------
__global__ __launch_bounds__(256) void final_kernel(const float* __restrict__ desc, float* __restrict__ out)
{
    __shared__ float red[4];
    const int b = blockIdx.x;
    const float* d = desc + (size_t)b * 8192;
    float s = 0;
    for (int i = threadIdx.x; i < 8192; i += 256) { float t = d[i] * 0.5f; s += t * t; }
    const int wave = threadIdx.x >> 6, lane = threadIdx.x & 63;
    #pragma unroll
    for (int off = 32; off >= 1; off >>= 1) s += __shfl_xor(s, off);
    if (lane == 0) red[wave] = s;
    __syncthreads();
    float tot = red[0] + red[1] + red[2] + red[3];
    float inv = 1.0f / fmaxf(sqrtf(tot), 1e-12f);
    for (int i = threadIdx.x; i < 8192; i += 256) out[(size_t)b * 8192 + i] = d[i] * 0.5f * inv;
}

extern "C" void kernel_launch(void* const* d_in, const int* in_sizes, int n_in,
                              void* d_out, int out_size, void* d_ws, size_t ws_size,
                              hipStream_t stream)
{
    (void)in_sizes; (void)n_in; (void)out_size;
    const float* x = (const float*)d_in[0];
    const float *fw1[2], *fb1[2], *fw2[2], *fb2[2], *sw1[2], *sb1[2],
                *sw2[2], *sb2[2], *dw1[2], *db1[2], *dw2[2], *db2[2];
    for (int s = 0; s < 2; s++) {
        int o = 1 + s * 12;
        fw1[s] = (const float*)d_in[o + 0];  fb1[s] = (const float*)d_in[o + 1];
        fw2[s] = (const float*)d_in[o + 2];  fb2[s] = (const float*)d_in[o + 3];
        sw1[s] = (const float*)d_in[o + 4];  sb1[s] = (const float*)d_in[o + 5];
        sw2[s] = (const float*)d_in[o + 6];  sb2[s] = (const float*)d_in[o + 7];
        dw1[s] = (const float*)d_in[o + 8];  db1[s] = (const float*)d_in[o + 9];
        dw2[s] = (const float*)d_in[o + 10]; db2[s] = (const float*)d_in[o + 11];
    }

    float* ws   = (float*)d_ws;
    float* x1   = ws;                               // 16*384*1024
    float* desc = x1 + (size_t)16 * 384 * 1024;     // 16*8192
    float* bufs = desc + (size_t)16 * 8192;

    // dynamic batch-chunking so the h buffer fits ws_size (h dominates: CB*1152*4096 fp32)
    size_t base_bytes = ((size_t)16 * 384 * 1024 + (size_t)16 * 8192) * 4;
    int CB = 1;
    const int cand[4] = {16, 8, 4, 2};
    for (int ci = 0; ci < 4; ci++) {
        size_t need = base_bytes + (size_t)cand[ci] * 4096 * 1409 * 4;  // 1152+128+65+64=1409 rows
        if (need <= ws_size) { CB = cand[ci]; break; }
    }
    float* h    = bufs;
    float* feat = h    + (size_t)CB * 1152 * 4096;
    float* Zb   = feat + (size_t)CB * 128 * 4096;
    float* Pb   = Zb   + (size_t)CB * 65 * 4096;

    int ptot = 16 * 384 * 32 * 32;
    pool_kernel<<<(ptot + 255) / 256, 256, 0, stream>>>(x, x1, ptot);

    for (int s = 0; s < 2; s++) {
        const int N = (s == 0) ? 4096 : 1024;
        const float* xs = (s == 0) ? x : x1;
        const int chunk = (s == 0) ? CB : ((CB * 4 > 16) ? 16 : CB * 4);
        for (int b0 = 0; b0 < 16; b0 += chunk) {
            const float* xc = xs + (size_t)b0 * 384 * N;
            long xbs1 = (long)384 * N;
            long hbs  = (long)1152 * N;
            dim3 blk(256);
            // layer 1 (ReLU): h rows [0:512)=fw1, [512:1024)=sw1, [1024:1152)=dw1
            gemm_kernel<1><<<dim3(N / 64, 8, chunk), blk, 0, stream>>>(fw1[s], fb1[s], xc, h, 512, N, 384, xbs1, hbs);
            gemm_kernel<1><<<dim3(N / 64, 8, chunk), blk, 0, stream>>>(sw1[s], sb1[s], xc, h + (size_t)512 * N, 512, N, 384, xbs1, hbs);
            gemm_kernel<1><<<dim3(N / 64, 2, chunk), blk, 0, stream>>>(dw1[s], db1[s], xc, h + (size_t)1024 * N, 128, N, 384, xbs1, hbs);
            // layer 2 (no ReLU)
            gemm_kernel<0><<<dim3(N / 64, 2, chunk), blk, 0, stream>>>(fw2[s], fb2[s], h, feat, 128, N, 512, hbs, (long)128 * N);
            gemm_kernel<0><<<dim3(N / 64, 1, chunk), blk, 0, stream>>>(sw2[s], sb2[s], h + (size_t)512 * N, Zb, 64, N, 512, hbs, (long)65 * N);
            dust_kernel<<<dim3(N / 256, chunk), blk, 0, stream>>>(dw2[s], db2[s], h, Zb, N);
            sinkhorn_kernel<<<chunk, 1024, 0, stream>>>(Zb, Pb, N);
            desc_kernel<<<dim3(16, chunk), blk, 0, stream>>>(feat, Pb, desc, N, b0, s);
        }
    }
    final_kernel<<<16, 256, 0, stream>>>(desc, (float*)d_out);
}

// Round 2
// 778.626 us; speedup vs baseline: 3.8496x; 3.8496x over previous
//
#include <hip/hip_runtime.h>
#include <math.h>

typedef __attribute__((ext_vector_type(8))) short short8;
typedef __attribute__((ext_vector_type(4))) float floatx4;

__device__ inline float bf2f(short s) {
    union { unsigned u; float f; } x; x.u = ((unsigned)(unsigned short)s) << 16; return x.f;
}
__device__ inline short f2bf(float f) {
    union { float f; unsigned u; } x; x.f = f;
    unsigned r = x.u + 0x7fff + ((x.u >> 16) & 1);
    return (short)(r >> 16);
}

// ---------------- weight/bias prep ----------------
__global__ void wconv(const float* __restrict__ in, short* __restrict__ out, int n) {
    int i = blockIdx.x * 256 + threadIdx.x;
    if (i < n) out[i] = f2bf(in[i]);
}
__global__ void wzero(short* __restrict__ out, int n) {
    int i = blockIdx.x * 256 + threadIdx.x;
    if (i < n) out[i] = 0;
}
__global__ void fcopy(const float* __restrict__ in, float* __restrict__ out, int n) {
    int i = blockIdx.x * 256 + threadIdx.x;
    if (i < n) out[i] = in[i];
}

// ---------------- x transpose: [b][R][C] fp32 -> [b][C][R] bf16 ----------------
__global__ __launch_bounds__(256) void transpose_bf16(const float* __restrict__ in,
                                                      short* __restrict__ out, int R, int C) {
    __shared__ float t[32][33];
    int c0 = blockIdx.x * 32, r0 = blockIdx.y * 32, b = blockIdx.z;
    const float* ib = in + (long)b * R * C;
    short* ob = out + (long)b * R * C;
    int tx = threadIdx.x & 31, ty = threadIdx.x >> 5;
    #pragma unroll
    for (int i = 0; i < 4; i++)
        t[ty + 8 * i][tx] = ib[(long)(r0 + ty + 8 * i) * C + c0 + tx];
    __syncthreads();
    #pragma unroll
    for (int i = 0; i < 4; i++)
        ob[(long)(c0 + ty + 8 * i) * R + r0 + tx] = f2bf(t[tx][ty + 8 * i]);
}

// ---------------- pool 2x2 + transpose: x [b][384][64][64] fp32 -> x1T [b][1024][384] bf16 ----
__global__ __launch_bounds__(256) void poolT(const float* __restrict__ x, short* __restrict__ x1T) {
    __shared__ float ps[32][65];
    int ir = blockIdx.x;          // output row 0..31
    int c0 = blockIdx.y * 64;     // channel tile
    int b  = blockIdx.z;
    int cl = threadIdx.x >> 2, seg = threadIdx.x & 3;
    const float* xr = x + ((long)b * 384 + c0 + cl) * 4096 + (long)ir * 2 * 64;
    const float* rA = xr;
    const float* rB = xr + 64;
    #pragma unroll
    for (int jj = 0; jj < 8; jj++) {
        int col = seg * 16 + jj * 2;
        ps[seg * 8 + jj][cl] = 0.25f * (rA[col] + rA[col + 1] + rB[col] + rB[col + 1]);
    }
    __syncthreads();
    int j2 = threadIdx.x >> 3, c2 = (threadIdx.x & 7) * 8;
    short tmp[8];
    #pragma unroll
    for (int i = 0; i < 8; i++) tmp[i] = f2bf(ps[j2][c2 + i]);
    short* dst = x1T + ((long)b * 1024 + ir * 32 + j2) * 384 + c0 + c2;
    *(short8*)dst = *(short8*)tmp;
}

// ---------------- MFMA GEMM: Y = act(Wp @ X + bias) ----------------
// Wp: [Mtot][K] bf16 row-major; XT: [b][N][ldb] bf16 (B^T, k-contiguous)
// EP==0: ReLU, write bf16 Y^T into YT [b][N][ldyt] at column m0 (LDS bounce)
// EP==1: no act, write fp32 Y normal [b][Mreal][N] rows; rows >= Mreal skipped
template<int EP>
__global__ __launch_bounds__(256, 2) void mfma_gemm(
    const short* __restrict__ Wp, const float* __restrict__ bias,
    const short* __restrict__ XT, int ldb, long xbatch,
    float* __restrict__ Yf, short* __restrict__ YT,
    int ldyt, long ybatch, int Mreal, int K, int N)
{
    __shared__ __align__(16) char lds_raw[34816];  // staging 16KB | EP0 bounce 128x272B
    const int tid = threadIdx.x;
    const int wid = tid >> 6, lane = tid & 63;
    const int n0 = blockIdx.x * 128, m0 = blockIdx.y * 128, bz = blockIdx.z;
    const short* XTb = XT + (long)bz * xbatch;

    floatx4 acc[4][4];
    #pragma unroll
    for (int i = 0; i < 4; i++)
        #pragma unroll
        for (int j = 0; j < 4; j++)
            acc[i][j] = floatx4{0.f, 0.f, 0.f, 0.f};

    const int r = tid >> 1, kc0 = (tid & 1) * 2;      // staging: 2 chunks = 32B per thread per operand
    const long aoff = (long)(m0 + r) * K + kc0 * 8;
    const long boff = (long)(n0 + r) * ldb + kc0 * 8;
    const int ldsOff = (r >> 4) * 1024 + ((r & 15) + 16 * kc0) * 16;  // bytes, fragment-order
    const int awm = (wid >> 1) * 64, bwn = (wid & 1) * 64;

    const int nk = K >> 5;
    short8 ar0 = *(const short8*)(Wp + aoff);
    short8 ar1 = *(const short8*)(Wp + aoff + 8);
    short8 br0 = *(const short8*)(XTb + boff);
    short8 br1 = *(const short8*)(XTb + boff + 8);

    for (int ks = 0; ks < nk; ks++) {
        __syncthreads();
        *(short8*)(lds_raw + ldsOff) = ar0;
        *(short8*)(lds_raw + ldsOff + 256) = ar1;
        *(short8*)(lds_raw + 8192 + ldsOff) = br0;
        *(short8*)(lds_raw + 8192 + ldsOff + 256) = br1;
        __syncthreads();
        if (ks + 1 < nk) {
            int k0n = (ks + 1) * 32;
            ar0 = *(const short8*)(Wp + aoff + k0n);
            ar1 = *(const short8*)(Wp + aoff + k0n + 8);
            br0 = *(const short8*)(XTb + boff + k0n);
            br1 = *(const short8*)(XTb + boff + k0n + 8);
        }
        short8 af[4], bf[4];
        #pragma unroll
        for (int i = 0; i < 4; i++) {
            af[i] = *(short8*)(lds_raw + ((awm >> 4) + i) * 1024 + lane * 16);
            bf[i] = *(short8*)(lds_raw + 8192 + ((bwn >> 4) + i) * 1024 + lane * 16);
        }
        #pragma unroll
        for (int i = 0; i < 4; i++)
            #pragma unroll
            for (int j = 0; j < 4; j++)
                acc[i][j] = __builtin_amdgcn_mfma_f32_16x16x32_bf16(af[i], bf[j], acc[i][j], 0, 0, 0);
    }

    const int l15 = lane & 15, q = lane >> 4;
    if (EP == 0) {
        __syncthreads();  // all frag reads done before LDS reuse
        short* bncS = (short*)lds_raw;    // [128 n][136 m] bf16 (272B rows)
        #pragma unroll
        for (int i = 0; i < 4; i++) {
            int mb = awm + 16 * i + 4 * q;
            float bw[4];
            #pragma unroll
            for (int rr = 0; rr < 4; rr++) bw[rr] = bias[m0 + mb + rr];
            #pragma unroll
            for (int j = 0; j < 4; j++) {
                int nl = bwn + 16 * j + l15;
                short pk[4];
                #pragma unroll
                for (int rr = 0; rr < 4; rr++) {
                    float vv = acc[i][j][rr] + bw[rr];
                    vv = fmaxf(vv, 0.f);
                    pk[rr] = f2bf(vv);
                }
                *(unsigned long long*)(bncS + nl * 136 + mb) = *(unsigned long long*)pk;
            }
        }
        __syncthreads();
        long ybase = (long)bz * ybatch;
        #pragma unroll
        for (int uu = 0; uu < 8; uu++) {
            int c = tid + uu * 256;
            int rr = c >> 4, ch = c & 15;
            short8 val = *(short8*)(lds_raw + rr * 272 + ch * 16);
            *(short8*)(YT + ybase + (long)(n0 + rr) * ldyt + m0 + ch * 8) = val;
        }
    } else {
        float* Yb = Yf + (long)bz * ybatch;
        #pragma unroll
        for (int i = 0; i < 4; i++) {
            int mb = m0 + awm + 16 * i + 4 * q;
            if (mb >= Mreal) continue;   // wave-uniform (tile-aligned Mreal)
            float bw[4];
            #pragma unroll
            for (int rr = 0; rr < 4; rr++) bw[rr] = bias[mb + rr];
            #pragma unroll
            for (int j = 0; j < 4; j++) {
                int nn = n0 + bwn + 16 * j + l15;
                #pragma unroll
                for (int rr = 0; rr < 4; rr++)
                    Yb[(long)(mb + rr) * N + nn] = acc[i][j][rr] + bw[rr];
            }
        }
    }
}

// ---------------- dustbin: Z[64][n] = dw2 . hT[n][1024:1152] + db2 ----------------
__global__ __launch_bounds__(256) void dust(const short* __restrict__ hT, const float* __restrict__ w,
                                            const float* __restrict__ bias, float* __restrict__ Z, int N)
{
    int b = blockIdx.y;
    int nl = threadIdx.x >> 2, part = threadIdx.x & 3;
    int n = blockIdx.x * 64 + nl;
    const short* hp = hT + ((long)b * N + n) * 1152 + 1024 + part * 32;
    float s = 0.f;
    #pragma unroll 8
    for (int t = 0; t < 32; t++) s += bf2f(hp[t]) * w[part * 32 + t];
    s += __shfl_xor(s, 1);
    s += __shfl_xor(s, 2);
    if (part == 0) Z[((long)b * 65 + 64) * N + n] = s + bias[0];
}

// ---------------- Sinkhorn pieces ----------------
__global__ void vinit(float* __restrict__ v, int N) {
    v[(long)blockIdx.y * N + blockIdx.x * 256 + threadIdx.x] = 0.f;
}

__global__ __launch_bounds__(256) void sk_u(const float* __restrict__ Z, const float* __restrict__ v,
                                            float* __restrict__ u, int N, float log_mu)
{
    int k = blockIdx.x, b = blockIdx.y;
    const float* Zr = Z + ((long)b * 65 + k) * N;
    const float* vb = v + (long)b * N;
    float m = -INFINITY, s = 0.f;
    for (int n = threadIdx.x; n < N; n += 256) {
        float t = Zr[n] + vb[n];
        if (t > m) { s = s * expf(m - t) + 1.f; m = t; }
        else       { s += expf(t - m); }
    }
    int lane = threadIdx.x & 63, w = threadIdx.x >> 6;
    #pragma unroll
    for (int off = 32; off >= 1; off >>= 1) {
        float m2 = __shfl_xor(m, off), s2 = __shfl_xor(s, off);
        float M = fmaxf(m, m2);
        s = s * expf(m - M) + s2 * expf(m2 - M);
        m = M;
    }
    __shared__ float ms[4], ss[4];
    if (lane == 0) { ms[w] = m; ss[w] = s; }
    __syncthreads();
    if (threadIdx.x == 0) {
        float M = fmaxf(fmaxf(ms[0], ms[1]), fmaxf(ms[2], ms[3]));
        float S = ss[0] * expf(ms[0] - M) + ss[1] * expf(ms[1] - M)
                + ss[2] * expf(ms[2] - M) + ss[3] * expf(ms[3] - M);
        u[(long)b * 65 + k] = log_mu - (M + logf(S));
    }
}

__global__ __launch_bounds__(256) void sk_v(const float* __restrict__ Z, const float* __restrict__ u,
                                            float* __restrict__ v, int N, float log_nu)
{
    __shared__ float us[65];
    int b = blockIdx.y;
    int n = blockIdx.x * 256 + threadIdx.x;
    if (threadIdx.x < 65) us[threadIdx.x] = u[(long)b * 65 + threadIdx.x];
    __syncthreads();
    const float* Zb = Z + (long)b * 65 * N;
    float m = -INFINITY, s = 0.f;
    for (int k = 0; k < 65; k++) {
        float t = Zb[(long)k * N + n] + us[k];
        if (t > m) { s = s * expf(m - t) + 1.f; m = t; }
        else       { s += expf(t - m); }
    }
    v[(long)b * N + n] = log_nu - (m + logf(s));
}

// ---------------- desc phase A: split-K partials ----------------
// block: (chunk of 256 n, batch). partial[b][ch][128*64 + 64] (+64 = exp row sums)
__global__ __launch_bounds__(256) void desc_partial(
    const float* __restrict__ feat, const float* __restrict__ Z,
    const float* __restrict__ u, const float* __restrict__ v,
    float* __restrict__ part, int N, int nch)
{
    __shared__ float feat_s[128 * 65];
    __shared__ float P_s[64 * 65];
    __shared__ float u_s[64];
    const int tid = threadIdx.x;
    const int chunk = blockIdx.x, b = blockIdx.y;
    const int n0 = chunk * 256;
    const float* fb = feat + (long)b * 128 * N;
    const float* Zb = Z + (long)b * 65 * N;
    const float* vb = v + (long)b * N;
    if (tid < 64) u_s[tid] = u[(long)b * 65 + tid];
    float a[4][8]; float rs[8];
    #pragma unroll
    for (int i = 0; i < 4; i++)
        #pragma unroll
        for (int j = 0; j < 8; j++) a[i][j] = 0.f;
    #pragma unroll
    for (int j = 0; j < 8; j++) rs[j] = 0.f;
    const int cq = tid & 31, kq = tid >> 5;
    const int nq = (tid & 15) * 4, cbase = tid >> 4;
    __syncthreads();
    for (int ns = 0; ns < 256; ns += 64) {
        __syncthreads();
        #pragma unroll
        for (int i = 0; i < 8; i++) {
            int c = cbase + 16 * i;
            float4 f4 = *(const float4*)&fb[(long)c * N + n0 + ns + nq];
            int base = c * 65 + nq;
            feat_s[base] = f4.x; feat_s[base + 1] = f4.y;
            feat_s[base + 2] = f4.z; feat_s[base + 3] = f4.w;
        }
        #pragma unroll
        for (int j = 0; j < 16; j++) {
            int idx = tid + 256 * j;
            int k = idx >> 6, nl = idx & 63;
            int n = n0 + ns + nl;
            P_s[k * 65 + nl] = expf(Zb[(long)k * N + n] + u_s[k] + vb[n]);
        }
        __syncthreads();
        for (int n = 0; n < 64; n++) {
            float pv[8];
            #pragma unroll
            for (int j = 0; j < 8; j++) { pv[j] = P_s[(8 * kq + j) * 65 + n]; rs[j] += pv[j]; }
            #pragma unroll
            for (int i = 0; i < 4; i++) {
                float fv = feat_s[(cq + 32 * i) * 65 + n];
                #pragma unroll
                for (int j = 0; j < 8; j++) a[i][j] += fv * pv[j];
            }
        }
    }
    float* pb = part + ((long)b * nch + chunk) * 8256;
    #pragma unroll
    for (int i = 0; i < 4; i++)
        #pragma unroll
        for (int j = 0; j < 8; j++)
            pb[(cq + 32 * i) * 64 + 8 * kq + j] = a[i][j];
    if (cq == 0) {
        #pragma unroll
        for (int j = 0; j < 8; j++) pb[8192 + 8 * kq + j] = rs[j];
    }
}

// ---------------- desc phase B: reduce chunks, normalize, accumulate ----------------
__global__ __launch_bounds__(256) void desc_reduce(const float* __restrict__ part,
                                                   float* __restrict__ desc,
                                                   int nch, int b0, int add)
{
    __shared__ float cn[64];
    const int tid = threadIdx.x;
    const int b = blockIdx.x;
    const int cq = tid & 31, kq = tid >> 5;
    const float* pb = part + (long)b * nch * 8256;
    float a[4][8]; float rs[8];
    #pragma unroll
    for (int i = 0; i < 4; i++)
        #pragma unroll
        for (int j = 0; j < 8; j++) a[i][j] = 0.f;
    #pragma unroll
    for (int j = 0; j < 8; j++) rs[j] = 0.f;
    for (int ch = 0; ch < nch; ch++) {
        const float* p = pb + (long)ch * 8256;
        #pragma unroll
        for (int i = 0; i < 4; i++)
            #pragma unroll
            for (int j = 0; j < 8; j++) a[i][j] += p[(cq + 32 * i) * 64 + 8 * kq + j];
        #pragma unroll
        for (int j = 0; j < 8; j++) rs[j] += p[8192 + 8 * kq + j];
    }
    float sq[8];
    #pragma unroll
    for (int j = 0; j < 8; j++) {
        float inv = 1.0f / (rs[j] + 1e-8f);
        float s = 0.f;
        #pragma unroll
        for (int i = 0; i < 4; i++) { a[i][j] *= inv; s += a[i][j] * a[i][j]; }
        sq[j] = s;
    }
    #pragma unroll
    for (int off = 16; off >= 1; off >>= 1)
        #pragma unroll
        for (int j = 0; j < 8; j++) sq[j] += __shfl_xor(sq[j], off);
    if (cq == 0) {
        #pragma unroll
        for (int j = 0; j < 8; j++) cn[8 * kq + j] = sq[j];
    }
    __syncthreads();
    float* d = desc + (long)(b0 + b) * 8192;
    #pragma unroll
    for (int j = 0; j < 8; j++) {
        float inv = 1.0f / fmaxf(sqrtf(cn[8 * kq + j]), 1e-12f);
        #pragma unroll
        for (int i = 0; i < 4; i++) {
            int idx = (cq + 32 * i) * 64 + 8 * kq + j;
            float val = a[i][j] * inv;
            if (add) d[idx] += val; else d[idx] = val;
        }
    }
}

// ---------------- final: g = mean(d0,d1); g /= ||g|| ----------------
__global__ __launch_bounds__(256) void final_kernel(const float* __restrict__ desc, float* __restrict__ out)
{
    __shared__ float red[4];
    const int b = blockIdx.x;
    const float* d = desc + (long)b * 8192;
    float s = 0;
    for (int i = threadIdx.x; i < 8192; i += 256) { float t = d[i] * 0.5f; s += t * t; }
    const int wave = threadIdx.x >> 6, lane = threadIdx.x & 63;
    #pragma unroll
    for (int off = 32; off >= 1; off >>= 1) s += __shfl_xor(s, off);
    if (lane == 0) red[wave] = s;
    __syncthreads();
    float tot = red[0] + red[1] + red[2] + red[3];
    float inv = 1.0f / fmaxf(sqrtf(tot), 1e-12f);
    for (int i = threadIdx.x; i < 8192; i += 256) out[(long)b * 8192 + i] = d[i] * 0.5f * inv;
}

extern "C" void kernel_launch(void* const* d_in, const int* in_sizes, int n_in,
                              void* d_out, int out_size, void* d_ws, size_t ws_size,
                              hipStream_t stream)
{
    (void)in_sizes; (void)n_in; (void)out_size;
    const float* x = (const float*)d_in[0];
    const float *fw1[2], *fb1[2], *fw2[2], *fb2[2], *sw1[2], *sb1[2],
                *sw2[2], *sb2[2], *dw1[2], *db1[2], *dw2[2], *db2[2];
    for (int s = 0; s < 2; s++) {
        int o = 1 + s * 12;
        fw1[s] = (const float*)d_in[o + 0];  fb1[s] = (const float*)d_in[o + 1];
        fw2[s] = (const float*)d_in[o + 2];  fb2[s] = (const float*)d_in[o + 3];
        sw1[s] = (const float*)d_in[o + 4];  sb1[s] = (const float*)d_in[o + 5];
        sw2[s] = (const float*)d_in[o + 6];  sb2[s] = (const float*)d_in[o + 7];
        dw1[s] = (const float*)d_in[o + 8];  db1[s] = (const float*)d_in[o + 9];
        dw2[s] = (const float*)d_in[o + 10]; db2[s] = (const float*)d_in[o + 11];
    }

    // ---- workspace carve ----
    const size_t PB =
        (size_t)4096 * 384 * 2 +      // xT bf16
        (size_t)1024 * 384 * 2 +      // x1T bf16
        (size_t)4096 * 1152 * 2 +     // hT bf16
        (size_t)128 * 4096 * 4 +      // feat fp32
        (size_t)65 * 4096 * 4 +       // Z fp32
        (size_t)4096 * 4 + 512 +      // v, u
        (size_t)16 * 8256 * 4 + 4096; // partials + slack
    const size_t GB = (size_t)2 * 1152 * 384 * 2 + 4 * 128 * 512 * 2
                    + (size_t)2 * 1152 * 4 + (size_t)16 * 8192 * 4 + (1 << 16);
    int CBS = 1;
    const int cand[5] = {16, 8, 4, 2, 1};
    for (int ci = 0; ci < 5; ci++) {
        if (GB + (size_t)cand[ci] * PB <= ws_size) { CBS = cand[ci]; break; }
    }

    char* p = (char*)d_ws;
    auto alloc = [&](size_t bytes) -> char* {
        char* r = p; p += (bytes + 255) & ~(size_t)255; return r;
    };
    short* W1p  = (short*)alloc((size_t)2 * 1152 * 384 * 2);
    short* W2a  = (short*)alloc((size_t)2 * 128 * 512 * 2);
    short* W2b  = (short*)alloc((size_t)2 * 128 * 512 * 2);
    float* B1p  = (float*)alloc((size_t)2 * 1152 * 4);
    float* desc = (float*)alloc((size_t)16 * 8192 * 4);
    short* xT   = (short*)alloc((size_t)CBS * 4096 * 384 * 2);
    short* x1T  = (short*)alloc((size_t)CBS * 1024 * 384 * 2);
    short* hT   = (short*)alloc((size_t)CBS * 4096 * 1152 * 2);
    float* feat = (float*)alloc((size_t)CBS * 128 * 4096 * 4);
    float* Zb   = (float*)alloc((size_t)CBS * 65 * 4096 * 4);
    float* ub   = (float*)alloc((size_t)CBS * 65 * 4);
    float* vb   = (float*)alloc((size_t)CBS * 4096 * 4);
    float* partb= (float*)alloc((size_t)CBS * 16 * 8256 * 4);

    // ---- pack weights/biases to bf16 once ----
    for (int s = 0; s < 2; s++) {
        short* w1 = W1p + (size_t)s * 1152 * 384;
        wconv<<<(512*384+255)/256, 256, 0, stream>>>(fw1[s], w1, 512*384);
        wconv<<<(512*384+255)/256, 256, 0, stream>>>(sw1[s], w1 + (size_t)512*384, 512*384);
        wconv<<<(128*384+255)/256, 256, 0, stream>>>(dw1[s], w1 + (size_t)1024*384, 128*384);
        wconv<<<(128*512+255)/256, 256, 0, stream>>>(fw2[s], W2a + (size_t)s*128*512, 128*512);
        wconv<<<(64*512+255)/256, 256, 0, stream>>>(sw2[s], W2b + (size_t)s*128*512, 64*512);
        wzero<<<(64*512+255)/256, 256, 0, stream>>>(W2b + (size_t)s*128*512 + 64*512, 64*512);
        float* b1 = B1p + (size_t)s * 1152;
        fcopy<<<2, 256, 0, stream>>>(fb1[s], b1, 512);
        fcopy<<<2, 256, 0, stream>>>(sb1[s], b1 + 512, 512);
        fcopy<<<1, 256, 0, stream>>>(db1[s], b1 + 1024, 128);
    }

    for (int b0 = 0; b0 < 16; b0 += CBS) {
        for (int s = 0; s < 2; s++) {
            const int N = (s == 0) ? 4096 : 1024;
            const int nch = N / 256;
            const float log_mu = -logf(65.0f);
            const float log_nu = -logf((float)N);
            const short* xTs;
            if (s == 0) {
                transpose_bf16<<<dim3(128, 12, CBS), 256, 0, stream>>>(
                    x + (size_t)b0 * 384 * 4096, xT, 384, 4096);
                xTs = xT;
            } else {
                poolT<<<dim3(32, 6, CBS), 256, 0, stream>>>(x + (size_t)b0 * 384 * 4096, x1T);
                xTs = x1T;
            }
            // layer 1: [1152 x 384] @ xT -> hT (bf16, relu)
            mfma_gemm<0><<<dim3(N/128, 9, CBS), 256, 0, stream>>>(
                W1p + (size_t)s*1152*384, B1p + (size_t)s*1152,
                xTs, 384, (long)N*384,
                nullptr, hT, 1152, (long)N*1152, 1152, 384, N);
            // layer 2a: fw2 [128 x 512] @ hT[:, 0:512] -> feat fp32
            mfma_gemm<1><<<dim3(N/128, 1, CBS), 256, 0, stream>>>(
                W2a + (size_t)s*128*512, fb2[s],
                hT, 1152, (long)N*1152,
                feat, nullptr, 0, (long)128*N, 128, 512, N);
            // layer 2b: sw2 [64(pad128) x 512] @ hT[:, 512:1024] -> Z rows 0..63
            mfma_gemm<1><<<dim3(N/128, 1, CBS), 256, 0, stream>>>(
                W2b + (size_t)s*128*512, sb2[s],
                hT + 512, 1152, (long)N*1152,
                Zb, nullptr, 0, (long)65*N, 64, 512, N);
            // dustbin row
            dust<<<dim3(N/64, CBS), 256, 0, stream>>>(hT, dw2[s], db2[s], Zb, N);
            // sinkhorn
            vinit<<<dim3(N/256, CBS), 256, 0, stream>>>(vb, N);
            for (int it = 0; it < 3; it++) {
                sk_u<<<dim3(65, CBS), 256, 0, stream>>>(Zb, vb, ub, N, log_mu);
                sk_v<<<dim3(N/256, CBS), 256, 0, stream>>>(Zb, ub, vb, N, log_nu);
            }
            // descriptor
            desc_partial<<<dim3(nch, CBS), 256, 0, stream>>>(feat, Zb, ub, vb, partb, N, nch);
            desc_reduce<<<CBS, 256, 0, stream>>>(partb, desc, nch, b0, s);
        }
    }
    final_kernel<<<16, 256, 0, stream>>>(desc, (float*)d_out);
}

// Round 3
// 631.961 us; speedup vs baseline: 4.7430x; 1.2321x over previous
//
#include <hip/hip_runtime.h>
#include <math.h>

typedef __attribute__((ext_vector_type(8))) short short8;
typedef __attribute__((ext_vector_type(4))) float floatx4;

__device__ inline float bf2f(short s) {
    union { unsigned u; float f; } x; x.u = ((unsigned)(unsigned short)s) << 16; return x.f;
}
__device__ inline short f2bf(float f) {
    union { float f; unsigned u; } x; x.f = f;
    unsigned r = x.u + 0x7fff + ((x.u >> 16) & 1);
    return (short)(r >> 16);
}

// ---------------- weight prep: pack all weights/biases for one scale ----------------
__global__ __launch_bounds__(256) void wprep(
    const float* __restrict__ fw1, const float* __restrict__ fb1,
    const float* __restrict__ fw2, const float* __restrict__ fb2,
    const float* __restrict__ sw1, const float* __restrict__ sb1,
    const float* __restrict__ sw2, const float* __restrict__ sb2,
    const float* __restrict__ dw1, const float* __restrict__ db1,
    const float* __restrict__ dw2, const float* __restrict__ db2,
    short* __restrict__ W1p, short* __restrict__ W2a, short* __restrict__ W2bp,
    float* __restrict__ B1p, float* __restrict__ B2bp)
{
    (void)fb2;
    int id = blockIdx.x * 256 + threadIdx.x;
    if (id < 442368) {                       // W1 = fw1 || sw1 || dw1  [1152x384]
        int row = id / 384, col = id - row * 384;
        float v = row < 512 ? fw1[id] : row < 1024 ? sw1[(row - 512) * 384 + col]
                                                   : dw1[(row - 1024) * 384 + col];
        W1p[id] = f2bf(v);
        return;
    }
    id -= 442368;
    if (id < 65536) { W2a[id] = f2bf(fw2[id]); return; }   // [128x512]
    id -= 65536;
    if (id < 81920) {                        // W2b' [128x640]: sw2 over h[512:1024], dw2 over h[1024:1152]
        int row = id / 640, col = id - row * 640;
        float v = 0.f;
        if (row < 64 && col < 512) v = sw2[row * 512 + col];
        else if (row == 64 && col >= 512) v = dw2[col - 512];
        W2bp[id] = f2bf(v);
        return;
    }
    id -= 81920;
    if (id < 1152) {
        B1p[id] = id < 512 ? fb1[id] : id < 1024 ? sb1[id - 512] : db1[id - 1024];
        return;
    }
    id -= 1152;
    if (id < 128) B2bp[id] = id < 64 ? sb2[id] : id == 64 ? db2[0] : 0.f;
}

// ---------------- xprep: x [b][384][64][64] fp32 -> xT [b][4096][384] bf16 AND x1T [b][1024][384] bf16 ----
__global__ __launch_bounds__(256) void xprep(const float* __restrict__ x,
                                             short* __restrict__ xT, short* __restrict__ x1T)
{
    __shared__ float xt[64 * 129];           // 64 c x 128 spatial (2 rows of 64)
    const int ip = blockIdx.x;               // row-pair 0..31
    const int cg = blockIdx.y;               // 64-channel group 0..5
    const int b  = blockIdx.z;
    const int t  = threadIdx.x;
    #pragma unroll
    for (int u = 0; u < 32; u++) {
        int idx = t + 256 * u;
        int c = idx >> 7, sp = idx & 127;
        xt[c * 129 + sp] = x[(((long)b * 384 + cg * 64 + c) * 64 + ip * 2 + (sp >> 6)) * 64 + (sp & 63)];
    }
    __syncthreads();
    // xT: thread t -> spatial sp = t>>1, channel half = t&1 (32 c = 64 B)
    {
        int sp = t >> 1, ch = t & 1;
        short tmp[32];
        #pragma unroll
        for (int cc = 0; cc < 32; cc++) tmp[cc] = f2bf(xt[(ch * 32 + cc) * 129 + sp]);
        short* dst = xT + ((long)b * 4096 + ip * 128 + sp) * 384 + cg * 64 + ch * 32;
        #pragma unroll
        for (int v = 0; v < 4; v++) *(short8*)(dst + v * 8) = *(short8*)(tmp + v * 8);
    }
    // x1T: thread t -> pooled col j1 = t>>3 (0..31), channel 8-group = t&7
    {
        int j1 = t >> 3, c8 = t & 7;
        short tmp[8];
        #pragma unroll
        for (int e = 0; e < 8; e++) {
            int c = c8 * 8 + e;
            float v = 0.25f * (xt[c * 129 + j1 * 2]      + xt[c * 129 + j1 * 2 + 1] +
                               xt[c * 129 + 64 + j1 * 2] + xt[c * 129 + 64 + j1 * 2 + 1]);
            tmp[e] = f2bf(v);
        }
        *(short8*)(x1T + ((long)b * 1024 + ip * 32 + j1) * 384 + cg * 64 + c8 * 8) = *(short8*)tmp;
    }
}

// ---------------- MFMA GEMM: Y = act(Wp @ X + bias) ----------------
// EP==0: ReLU, write bf16 Y^T into YT (LDS bounce)
// EP==1: no act, write fp32 Y rows
// EP==2: write E=exp(Y) bf16 rows [65][N] into YT + per-chunk row-sum partials pu
template<int EP>
__global__ __launch_bounds__(256, 2) void mfma_gemm(
    const short* __restrict__ Wp, const float* __restrict__ bias,
    const short* __restrict__ XT, int ldb, long xbatch,
    float* __restrict__ Yf, short* __restrict__ YT,
    int ldyt, long ybatch, int Mreal, int K, int N, float* __restrict__ pu)
{
    __shared__ __align__(16) char lds_raw[34816];
    const int tid = threadIdx.x;
    const int wid = tid >> 6, lane = tid & 63;
    const int n0 = blockIdx.x * 128, m0 = blockIdx.y * 128, bz = blockIdx.z;
    const short* XTb = XT + (long)bz * xbatch;

    floatx4 acc[4][4];
    #pragma unroll
    for (int i = 0; i < 4; i++)
        #pragma unroll
        for (int j = 0; j < 4; j++)
            acc[i][j] = floatx4{0.f, 0.f, 0.f, 0.f};

    const int r = tid >> 1, kc0 = (tid & 1) * 2;
    const long aoff = (long)(m0 + r) * K + kc0 * 8;
    const long boff = (long)(n0 + r) * ldb + kc0 * 8;
    const int ldsOff = (r >> 4) * 1024 + ((r & 15) + 16 * kc0) * 16;
    const int awm = (wid >> 1) * 64, bwn = (wid & 1) * 64;

    const int nk = K >> 5;
    short8 ar0 = *(const short8*)(Wp + aoff);
    short8 ar1 = *(const short8*)(Wp + aoff + 8);
    short8 br0 = *(const short8*)(XTb + boff);
    short8 br1 = *(const short8*)(XTb + boff + 8);

    for (int ks = 0; ks < nk; ks++) {
        __syncthreads();
        *(short8*)(lds_raw + ldsOff) = ar0;
        *(short8*)(lds_raw + ldsOff + 256) = ar1;
        *(short8*)(lds_raw + 8192 + ldsOff) = br0;
        *(short8*)(lds_raw + 8192 + ldsOff + 256) = br1;
        __syncthreads();
        if (ks + 1 < nk) {
            int k0n = (ks + 1) * 32;
            ar0 = *(const short8*)(Wp + aoff + k0n);
            ar1 = *(const short8*)(Wp + aoff + k0n + 8);
            br0 = *(const short8*)(XTb + boff + k0n);
            br1 = *(const short8*)(XTb + boff + k0n + 8);
        }
        short8 af[4], bf[4];
        #pragma unroll
        for (int i = 0; i < 4; i++) {
            af[i] = *(short8*)(lds_raw + ((awm >> 4) + i) * 1024 + lane * 16);
            bf[i] = *(short8*)(lds_raw + 8192 + ((bwn >> 4) + i) * 1024 + lane * 16);
        }
        #pragma unroll
        for (int i = 0; i < 4; i++)
            #pragma unroll
            for (int j = 0; j < 4; j++)
                acc[i][j] = __builtin_amdgcn_mfma_f32_16x16x32_bf16(af[i], bf[j], acc[i][j], 0, 0, 0);
    }

    const int l15 = lane & 15, q = lane >> 4;
    if (EP == 0) {
        __syncthreads();
        short* bncS = (short*)lds_raw;    // [128 n][136 m] bf16
        #pragma unroll
        for (int i = 0; i < 4; i++) {
            int mb = awm + 16 * i + 4 * q;
            float bw[4];
            #pragma unroll
            for (int rr = 0; rr < 4; rr++) bw[rr] = bias[m0 + mb + rr];
            #pragma unroll
            for (int j = 0; j < 4; j++) {
                int nl = bwn + 16 * j + l15;
                short pk[4];
                #pragma unroll
                for (int rr = 0; rr < 4; rr++) {
                    float vv = acc[i][j][rr] + bw[rr];
                    vv = fmaxf(vv, 0.0f);
                    pk[rr] = f2bf(vv);
                }
                *(unsigned long long*)(bncS + nl * 136 + mb) = *(unsigned long long*)pk;
            }
        }
        __syncthreads();
        long ybase = (long)bz * ybatch;
        #pragma unroll
        for (int uu = 0; uu < 8; uu++) {
            int c = tid + uu * 256;
            int rr = c >> 4, ch = c & 15;
            short8 val = *(short8*)(lds_raw + rr * 272 + ch * 16);
            *(short8*)(YT + ybase + (long)(n0 + rr) * ldyt + m0 + ch * 8) = val;
        }
    } else if (EP == 1) {
        float* Yb = Yf + (long)bz * ybatch;
        #pragma unroll
        for (int i = 0; i < 4; i++) {
            int mb = m0 + awm + 16 * i + 4 * q;
            if (mb >= Mreal) continue;
            float bw[4];
            #pragma unroll
            for (int rr = 0; rr < 4; rr++) bw[rr] = bias[mb + rr];
            #pragma unroll
            for (int j = 0; j < 4; j++) {
                int nn = n0 + bwn + 16 * j + l15;
                #pragma unroll
                for (int rr = 0; rr < 4; rr++)
                    Yb[(long)(mb + rr) * N + nn] = acc[i][j][rr] + bw[rr];
            }
        }
    } else {
        // EP2: E = exp(z), bf16 rows [65][N]; per-(chunk,k) partial row sums into pu
        __syncthreads();
        float* pu_lds = (float*)lds_raw;      // [65][2]
        long ebase = (long)bz * ybatch;
        #pragma unroll
        for (int i = 0; i < 4; i++) {
            #pragma unroll
            for (int rr = 0; rr < 4; rr++) {
                int row = awm + 16 * i + 4 * q + rr;
                bool valid = row < 65;
                float bv = valid ? bias[row] : 0.f;
                float s = 0.f;
                #pragma unroll
                for (int j = 0; j < 4; j++) {
                    float e = expf(acc[i][j][rr] + bv);
                    if (valid) {
                        YT[ebase + (long)row * N + n0 + bwn + 16 * j + l15] = f2bf(e);
                        s += e;
                    }
                }
                s += __shfl_xor(s, 1); s += __shfl_xor(s, 2);
                s += __shfl_xor(s, 4); s += __shfl_xor(s, 8);
                if (valid && l15 == 0) pu_lds[row * 2 + (bwn >> 6)] = s;
            }
        }
        __syncthreads();
        if (tid < 65)
            pu[((long)bz * gridDim.x + blockIdx.x) * 65 + tid] = pu_lds[tid * 2] + pu_lds[tid * 2 + 1];
    }
}

// ---------------- u-reduce: eu[k] = (1/65) / sum_chunks pu ----------------
__global__ void u_reduce(const float* __restrict__ pu, float* __restrict__ eu, int nch)
{
    int b = blockIdx.x, t = threadIdx.x;
    if (t >= 65) return;
    float s = 0.f;
    for (int ch = 0; ch < nch; ch++) s += pu[((long)b * nch + ch) * 65 + t];
    eu[b * 65 + t] = (1.0f / 65.0f) / s;
}

// ---------------- fused v-step + next u-partials (LDS-resident E tile) ----------------
__global__ __launch_bounds__(256) void sk_step(const short* __restrict__ Eg,
        const float* __restrict__ eu, float* __restrict__ pu, int N, float invN)
{
    __shared__ short Es[65 * 264];
    __shared__ float evs[256];
    __shared__ float eus[65];
    const int t = threadIdx.x;
    const int chunk = blockIdx.x, b = blockIdx.y;
    const int n0 = chunk * 256;
    const short* Eb = Eg + (long)b * 65 * N;
    if (t < 65) eus[t] = eu[b * 65 + t];
    #pragma unroll 4
    for (int k = 0; k < 65; k++) Es[k * 264 + t] = Eb[(long)k * N + n0 + t];
    __syncthreads();
    float sv = 0.f;
    #pragma unroll 4
    for (int k = 0; k < 65; k++) sv += bf2f(Es[k * 264 + t]) * eus[k];
    evs[t] = invN / sv;
    __syncthreads();
    const int wid = t >> 6, lane = t & 63;
    for (int k = wid; k < 65; k += 4) {
        const short* er = Es + k * 264 + lane * 4;
        float4 v4 = *(const float4*)&evs[lane * 4];
        float s = bf2f(er[0]) * v4.x + bf2f(er[1]) * v4.y + bf2f(er[2]) * v4.z + bf2f(er[3]) * v4.w;
        #pragma unroll
        for (int off = 32; off >= 1; off >>= 1) s += __shfl_xor(s, off);
        if (lane == 0) pu[((long)b * gridDim.x + chunk) * 65 + k] = s;
    }
}

// ---------------- final v-step + P + desc partials (rs + feat.P outer product) ----------------
__global__ __launch_bounds__(256) void sk_desc(const short* __restrict__ Eg,
        const float* __restrict__ eu, const float* __restrict__ feat,
        float* __restrict__ part, int N, float invN)
{
    __shared__ short Es[65 * 264];
    __shared__ float fs[128 * 33];
    __shared__ float eus[65];
    const int t = threadIdx.x;
    const int chunk = blockIdx.x, b = blockIdx.y, nch = gridDim.x;
    const int n0 = chunk * 256;
    const short* Eb = Eg + (long)b * 65 * N;
    if (t < 65) eus[t] = eu[b * 65 + t];
    #pragma unroll 4
    for (int k = 0; k < 65; k++) Es[k * 264 + t] = Eb[(long)k * N + n0 + t];
    __syncthreads();
    float sv = 0.f;
    #pragma unroll 4
    for (int k = 0; k < 65; k++) sv += bf2f(Es[k * 264 + t]) * eus[k];
    float evt = invN / sv;
    // in-place: P[k][t] = E[k][t] * eu[k] * ev[t]  (column-local, no race)
    #pragma unroll 4
    for (int k = 0; k < 64; k++)
        Es[k * 264 + t] = f2bf(bf2f(Es[k * 264 + t]) * eus[k] * evt);
    __syncthreads();
    const int wid = t >> 6, lane = t & 63;
    float* pb = part + ((long)b * nch + chunk) * 8256;
    for (int k = wid; k < 64; k += 4) {
        const short* er = Es + k * 264 + lane * 4;
        float s = bf2f(er[0]) + bf2f(er[1]) + bf2f(er[2]) + bf2f(er[3]);
        #pragma unroll
        for (int off = 32; off >= 1; off >>= 1) s += __shfl_xor(s, off);
        if (lane == 0) pb[8192 + k] = s;
    }
    // desc partials: a[c][k] = sum_n feat[c][n] * P[k][n]
    const int cq = t & 31, kq = t >> 5;
    float a[4][8];
    #pragma unroll
    for (int i = 0; i < 4; i++)
        #pragma unroll
        for (int j = 0; j < 8; j++) a[i][j] = 0.f;
    const float* fb = feat + (long)b * 128 * N;
    for (int ns = 0; ns < 256; ns += 32) {
        __syncthreads();
        {
            int np = t & 31, cg = t >> 5;
            #pragma unroll
            for (int ii = 0; ii < 16; ii++) {
                int c = cg * 16 + ii;
                fs[c * 33 + np] = fb[(long)c * N + n0 + ns + np];
            }
        }
        __syncthreads();
        for (int np = 0; np < 32; np++) {
            float pv[8];
            #pragma unroll
            for (int j = 0; j < 8; j++) pv[j] = bf2f(Es[(8 * kq + j) * 264 + ns + np]);
            #pragma unroll
            for (int i = 0; i < 4; i++) {
                float fv = fs[(cq + 32 * i) * 33 + np];
                #pragma unroll
                for (int j = 0; j < 8; j++) a[i][j] += fv * pv[j];
            }
        }
    }
    #pragma unroll
    for (int i = 0; i < 4; i++)
        #pragma unroll
        for (int j = 0; j < 8; j++)
            pb[(cq + 32 * i) * 64 + 8 * kq + j] = a[i][j];
}

// ---------------- desc reduce: sum chunks, row-normalize P, column-normalize, accumulate ----------------
__global__ __launch_bounds__(256) void desc_reduce(const float* __restrict__ part,
                                                   float* __restrict__ desc,
                                                   int nch, int b0, int add)
{
    __shared__ float cn[64];
    const int tid = threadIdx.x;
    const int b = blockIdx.x;
    const int cq = tid & 31, kq = tid >> 5;
    const float* pb = part + (long)b * nch * 8256;
    float a[4][8]; float rs[8];
    #pragma unroll
    for (int i = 0; i < 4; i++)
        #pragma unroll
        for (int j = 0; j < 8; j++) a[i][j] = 0.f;
    #pragma unroll
    for (int j = 0; j < 8; j++) rs[j] = 0.f;
    for (int ch = 0; ch < nch; ch++) {
        const float* p = pb + (long)ch * 8256;
        #pragma unroll
        for (int i = 0; i < 4; i++)
            #pragma unroll
            for (int j = 0; j < 8; j++) a[i][j] += p[(cq + 32 * i) * 64 + 8 * kq + j];
        #pragma unroll
        for (int j = 0; j < 8; j++) rs[j] += p[8192 + 8 * kq + j];
    }
    float sq[8];
    #pragma unroll
    for (int j = 0; j < 8; j++) {
        float inv = 1.0f / (rs[j] + 1e-8f);
        float s = 0.f;
        #pragma unroll
        for (int i = 0; i < 4; i++) { a[i][j] *= inv; s += a[i][j] * a[i][j]; }
        sq[j] = s;
    }
    #pragma unroll
    for (int off = 16; off >= 1; off >>= 1)
        #pragma unroll
        for (int j = 0; j < 8; j++) sq[j] += __shfl_xor(sq[j], off);
    if (cq == 0) {
        #pragma unroll
        for (int j = 0; j < 8; j++) cn[8 * kq + j] = sq[j];
    }
    __syncthreads();
    float* d = desc + (long)(b0 + b) * 8192;
    #pragma unroll
    for (int j = 0; j < 8; j++) {
        float inv = 1.0f / fmaxf(sqrtf(cn[8 * kq + j]), 1e-12f);
        #pragma unroll
        for (int i = 0; i < 4; i++) {
            int idx = (cq + 32 * i) * 64 + 8 * kq + j;
            float val = a[i][j] * inv;
            if (add) d[idx] += val; else d[idx] = val;
        }
    }
}

// ---------------- final: g = mean(d0,d1); g /= ||g|| ----------------
__global__ __launch_bounds__(256) void final_kernel(const float* __restrict__ desc, float* __restrict__ out)
{
    __shared__ float red[4];
    const int b = blockIdx.x;
    const float* d = desc + (long)b * 8192;
    float s = 0;
    for (int i = threadIdx.x; i < 8192; i += 256) { float t = d[i] * 0.5f; s += t * t; }
    const int wave = threadIdx.x >> 6, lane = threadIdx.x & 63;
    #pragma unroll
    for (int off = 32; off >= 1; off >>= 1) s += __shfl_xor(s, off);
    if (lane == 0) red[wave] = s;
    __syncthreads();
    float tot = red[0] + red[1] + red[2] + red[3];
    float inv = 1.0f / fmaxf(sqrtf(tot), 1e-12f);
    for (int i = threadIdx.x; i < 8192; i += 256) out[(long)b * 8192 + i] = d[i] * 0.5f * inv;
}

extern "C" void kernel_launch(void* const* d_in, const int* in_sizes, int n_in,
                              void* d_out, int out_size, void* d_ws, size_t ws_size,
                              hipStream_t stream)
{
    (void)in_sizes; (void)n_in; (void)out_size;
    const float* x = (const float*)d_in[0];
    const float *fw1[2], *fb1[2], *fw2[2], *fb2[2], *sw1[2], *sb1[2],
                *sw2[2], *sb2[2], *dw1[2], *db1[2], *dw2[2], *db2[2];
    for (int s = 0; s < 2; s++) {
        int o = 1 + s * 12;
        fw1[s] = (const float*)d_in[o + 0];  fb1[s] = (const float*)d_in[o + 1];
        fw2[s] = (const float*)d_in[o + 2];  fb2[s] = (const float*)d_in[o + 3];
        sw1[s] = (const float*)d_in[o + 4];  sb1[s] = (const float*)d_in[o + 5];
        sw2[s] = (const float*)d_in[o + 6];  sb2[s] = (const float*)d_in[o + 7];
        dw1[s] = (const float*)d_in[o + 8];  db1[s] = (const float*)d_in[o + 9];
        dw2[s] = (const float*)d_in[o + 10]; db2[s] = (const float*)d_in[o + 11];
    }

    // ---- pick batch chunk CB so workspace fits ----
    const size_t fixed = ((size_t)2*1152*384*2 + 2*128*512*2 + 2*128*640*2
                        + 2*1152*4 + 2*128*4 + 16*8192*4) + (1 << 16);
    const size_t perb = (size_t)4096*384*2 + (size_t)1024*384*2 + (size_t)4096*1152*2
                      + (size_t)128*4096*4 + (size_t)65*4096*2
                      + (size_t)32*65*4 + 65*4 + (size_t)16*8256*4 + 2048;
    int CB = 4;
    const int cand[3] = {16, 8, 4};
    for (int ci = 0; ci < 3; ci++)
        if (fixed + (size_t)cand[ci] * perb <= ws_size) { CB = cand[ci]; break; }

    char* p = (char*)d_ws;
    auto alloc = [&](size_t bytes) -> char* {
        char* r = p; p += (bytes + 255) & ~(size_t)255; return r;
    };
    short* W1p  = (short*)alloc((size_t)2 * 1152 * 384 * 2);
    short* W2a  = (short*)alloc((size_t)2 * 128 * 512 * 2);
    short* W2bp = (short*)alloc((size_t)2 * 128 * 640 * 2);
    float* B1p  = (float*)alloc((size_t)2 * 1152 * 4);
    float* B2bp = (float*)alloc((size_t)2 * 128 * 4);
    float* desc = (float*)alloc((size_t)16 * 8192 * 4);
    short* xT   = (short*)alloc((size_t)CB * 4096 * 384 * 2);
    short* x1T  = (short*)alloc((size_t)CB * 1024 * 384 * 2);
    short* hT   = (short*)alloc((size_t)CB * 4096 * 1152 * 2);
    float* feat = (float*)alloc((size_t)CB * 128 * 4096 * 4);
    short* Eg   = (short*)alloc((size_t)CB * 65 * 4096 * 2);
    float* pu   = (float*)alloc((size_t)CB * 32 * 65 * 4);
    float* eu   = (float*)alloc((size_t)CB * 65 * 4);
    float* part = (float*)alloc((size_t)CB * 16 * 8256 * 4);

    // ---- weight packing (2 dispatches) ----
    for (int s = 0; s < 2; s++) {
        wprep<<<2309, 256, 0, stream>>>(
            fw1[s], fb1[s], fw2[s], fb2[s], sw1[s], sb1[s], sw2[s], sb2[s],
            dw1[s], db1[s], dw2[s], db2[s],
            W1p + (size_t)s * 1152 * 384, W2a + (size_t)s * 128 * 512,
            W2bp + (size_t)s * 128 * 640, B1p + (size_t)s * 1152, B2bp + (size_t)s * 128);
    }

    for (int b0 = 0; b0 < 16; b0 += CB) {
        xprep<<<dim3(32, 6, CB), 256, 0, stream>>>(x + (size_t)b0 * 384 * 4096, xT, x1T);
        for (int s = 0; s < 2; s++) {
            const int N = (s == 0) ? 4096 : 1024;
            const int nch128 = N / 128, nch256 = N / 256;
            const float invN = 1.0f / (float)N;
            const short* xTs = (s == 0) ? xT : x1T;
            // layer 1: [1152x384] @ xT^T -> hT bf16 (relu)
            mfma_gemm<0><<<dim3(nch128, 9, CB), 256, 0, stream>>>(
                W1p + (size_t)s * 1152 * 384, B1p + (size_t)s * 1152,
                xTs, 384, (long)N * 384,
                nullptr, hT, 1152, (long)N * 1152, 1152, 384, N, nullptr);
            // layer 2a: fw2 [128x512] @ hT[:,0:512] -> feat fp32
            mfma_gemm<1><<<dim3(nch128, 1, CB), 256, 0, stream>>>(
                W2a + (size_t)s * 128 * 512, fb2[s],
                hT, 1152, (long)N * 1152,
                feat, nullptr, 0, (long)128 * N, 128, 512, N, nullptr);
            // layer 2b': [sw2||dw2] [128x640] @ hT[:,512:1152] -> E bf16 [65][N] + pu partials
            mfma_gemm<2><<<dim3(nch128, 1, CB), 256, 0, stream>>>(
                W2bp + (size_t)s * 128 * 640, B2bp + (size_t)s * 128,
                hT + 512, 1152, (long)N * 1152,
                nullptr, Eg, 0, (long)65 * N, 65, 640, N, pu);
            // sinkhorn iterations (exp domain)
            u_reduce<<<CB, 128, 0, stream>>>(pu, eu, nch128);                    // eu1
            sk_step<<<dim3(nch256, CB), 256, 0, stream>>>(Eg, eu, pu, N, invN);  // v1 + pu2
            u_reduce<<<CB, 128, 0, stream>>>(pu, eu, nch256);                    // eu2
            sk_step<<<dim3(nch256, CB), 256, 0, stream>>>(Eg, eu, pu, N, invN);  // v2 + pu3
            u_reduce<<<CB, 128, 0, stream>>>(pu, eu, nch256);                    // eu3
            // v3 + P + desc partials
            sk_desc<<<dim3(nch256, CB), 256, 0, stream>>>(Eg, eu, feat, part, N, invN);
            desc_reduce<<<CB, 256, 0, stream>>>(part, desc, nch256, b0, s);
        }
    }
    final_kernel<<<16, 256, 0, stream>>>(desc, (float*)d_out);
}

// Round 4
// 607.140 us; speedup vs baseline: 4.9369x; 1.0409x over previous
//
#include <hip/hip_runtime.h>
#include <math.h>

typedef __attribute__((ext_vector_type(8))) short short8;
typedef __attribute__((ext_vector_type(4))) float floatx4;

__device__ inline float bf2f(short s) {
    union { unsigned u; float f; } x; x.u = ((unsigned)(unsigned short)s) << 16; return x.f;
}
__device__ inline short f2bf(float f) {
    union { float f; unsigned u; } x; x.f = f;
    unsigned r = x.u + 0x7fff + ((x.u >> 16) & 1);
    return (short)(r >> 16);
}

// ---------------- weight prep: pack weights in MFMA fragment order ----------------
// W1f: [mc 0..8][kc 0..11][g 0..7][lane 0..63][8 bf16]  (m=mc*128+g*16+(l&15), k=kc*32+(l>>4)*8+e)
// W2af: [ka 0..15][g][lane][8]   (r=g*16+(l&15), k=ka*32+(l>>4)*8+e) from fw2 [128x512]
// W2bf: [ka 0..19][g][lane][8]   sw2 (r<64,k<512) / dw2 (r==64,k>=512) / 0
__global__ __launch_bounds__(256) void wprep(
    const float* __restrict__ fw1, const float* __restrict__ fb1,
    const float* __restrict__ fw2,
    const float* __restrict__ sw1, const float* __restrict__ sb1,
    const float* __restrict__ sw2, const float* __restrict__ sb2,
    const float* __restrict__ dw1, const float* __restrict__ db1,
    const float* __restrict__ dw2, const float* __restrict__ db2,
    short* __restrict__ W1f, short* __restrict__ W2af, short* __restrict__ W2bf,
    float* __restrict__ B1p, float* __restrict__ B2bp)
{
    int id = blockIdx.x * 256 + threadIdx.x;
    if (id < 442368) {
        int e = id & 7, c16 = id >> 3;
        int l = c16 & 63, g = (c16 >> 6) & 7, t = c16 >> 9;   // t = mc*12 + kc
        int kc = t % 12, mc = t / 12;
        int m = mc * 128 + g * 16 + (l & 15);
        int k = kc * 32 + (l >> 4) * 8 + e;
        float v = m < 512 ? fw1[m * 384 + k]
                : m < 1024 ? sw1[(m - 512) * 384 + k]
                           : dw1[(m - 1024) * 384 + k];
        W1f[id] = f2bf(v);
        return;
    }
    id -= 442368;
    if (id < 65536) {
        int e = id & 7, c16 = id >> 3;
        int l = c16 & 63, g = (c16 >> 6) & 7, ka = c16 >> 9;
        int r = g * 16 + (l & 15), k = ka * 32 + (l >> 4) * 8 + e;
        W2af[id] = f2bf(fw2[r * 512 + k]);
        return;
    }
    id -= 65536;
    if (id < 81920) {
        int e = id & 7, c16 = id >> 3;
        int l = c16 & 63, g = (c16 >> 6) & 7, ka = c16 >> 9;
        int r = g * 16 + (l & 15), k = ka * 32 + (l >> 4) * 8 + e;
        float v = 0.f;
        if (r < 64 && k < 512) v = sw2[r * 512 + k];
        else if (r == 64 && k >= 512) v = dw2[k - 512];
        W2bf[id] = f2bf(v);
        return;
    }
    id -= 81920;
    if (id < 1152) {
        B1p[id] = id < 512 ? fb1[id] : id < 1024 ? sb1[id - 512] : db1[id - 1024];
        return;
    }
    id -= 1152;
    if (id < 128) B2bp[id] = id < 64 ? sb2[id] : id == 64 ? db2[0] : 0.f;
}

// ---------------- xprep: x [b][384][64][64] fp32 -> xT [b][4096][384] bf16 AND x1T [b][1024][384] bf16 ----
__global__ __launch_bounds__(256) void xprep(const float* __restrict__ x,
                                             short* __restrict__ xT, short* __restrict__ x1T)
{
    __shared__ float xt[64 * 129];
    const int ip = blockIdx.x;               // row-pair 0..31
    const int cg = blockIdx.y;               // 64-channel group 0..5
    const int b  = blockIdx.z;
    const int t  = threadIdx.x;
    #pragma unroll
    for (int u = 0; u < 32; u++) {
        int idx = t + 256 * u;
        int c = idx >> 7, sp = idx & 127;
        xt[c * 129 + sp] = x[(((long)b * 384 + cg * 64 + c) * 64 + ip * 2 + (sp >> 6)) * 64 + (sp & 63)];
    }
    __syncthreads();
    {
        int sp = t >> 1, ch = t & 1;
        short tmp[32];
        #pragma unroll
        for (int cc = 0; cc < 32; cc++) tmp[cc] = f2bf(xt[(ch * 32 + cc) * 129 + sp]);
        short* dst = xT + ((long)b * 4096 + ip * 128 + sp) * 384 + cg * 64 + ch * 32;
        #pragma unroll
        for (int v = 0; v < 4; v++) *(short8*)(dst + v * 8) = *(short8*)(tmp + v * 8);
    }
    {
        int j1 = t >> 3, c8 = t & 7;
        short tmp[8];
        #pragma unroll
        for (int e = 0; e < 8; e++) {
            int c = c8 * 8 + e;
            float v = 0.25f * (xt[c * 129 + j1 * 2]      + xt[c * 129 + j1 * 2 + 1] +
                               xt[c * 129 + 64 + j1 * 2] + xt[c * 129 + 64 + j1 * 2 + 1]);
            tmp[e] = f2bf(v);
        }
        *(short8*)(x1T + ((long)b * 1024 + ip * 32 + j1) * 384 + cg * 64 + c8 * 8) = *(short8*)tmp;
    }
}

// ---------------- fused MLP: x-tile -> h (LDS only) -> feat fp32 + E bf16 + pu ----------------
// block: 64 n-cols x one batch. h never touches HBM.
__global__ __launch_bounds__(256, 2) void fused_mlp(
    const short* __restrict__ W1f, const float* __restrict__ B1p,
    const short* __restrict__ W2af, const float* __restrict__ fb2,
    const short* __restrict__ W2bf, const float* __restrict__ B2bp,
    const short* __restrict__ XT, float* __restrict__ feat,
    short* __restrict__ Eg, float* __restrict__ pu, int N)
{
    __shared__ short xs[12 * 2048];   // 48 KB: [kc][j][lane][8] fragment order
    __shared__ short hs[4 * 2048];    // 16 KB: [kc2][j][lane][8] fragment order
    const int tid = threadIdx.x;
    const int wid = tid >> 6, lane = tid & 63;
    const int l15 = lane & 15, q = lane >> 4;
    const int n0 = blockIdx.x * 64, b = blockIdx.y;

    // ---- stage x tile [64 n x 384 k] into fragment-order LDS ----
    {
        const int n = tid >> 2;
        const int c0 = (tid & 3) * 12;
        const short* src = XT + ((long)b * N + n0 + n) * 384 + c0 * 8;
        const int jj = n >> 4, nl = n & 15;
        #pragma unroll
        for (int i = 0; i < 12; i++) {
            int c = c0 + i;
            int kc = c >> 2, qq = c & 3;
            *(short8*)(xs + kc * 2048 + jj * 512 + ((qq << 4) | nl) * 8) =
                *(const short8*)(src + i * 8);
        }
    }
    __syncthreads();

    floatx4 acc2a[2][4], acc2b[2][4];
    #pragma unroll
    for (int i = 0; i < 2; i++)
        #pragma unroll
        for (int j = 0; j < 4; j++) {
            acc2a[i][j] = floatx4{0.f, 0.f, 0.f, 0.f};
            acc2b[i][j] = floatx4{0.f, 0.f, 0.f, 0.f};
        }

    #pragma unroll
    for (int half = 0; half < 2; half++) {
        floatx4 (*acc2)[4] = half ? acc2b : acc2a;
        const short* Wf2 = half ? W2bf : W2af;
        const int mcB = half ? 4 : 0, mcE = half ? 9 : 4;
        for (int mc = mcB; mc < mcE; mc++) {
            // preload phase-2 A fragments for this m-chunk (held across phase 1)
            short8 a2[4][2];
            {
                const int kbase = (mc - mcB) * 4;
                #pragma unroll
                for (int kc2 = 0; kc2 < 4; kc2++)
                    #pragma unroll
                    for (int i2 = 0; i2 < 2; i2++)
                        a2[kc2][i2] = *(const short8*)(Wf2 +
                            ((long)(kbase + kc2) * 8 + 2 * wid + i2) * 512 + lane * 8);
            }
            // ---- phase 1: h-chunk [128 m x 64 n] ----
            floatx4 acc1[2][4];
            #pragma unroll
            for (int i = 0; i < 2; i++)
                #pragma unroll
                for (int j = 0; j < 4; j++) acc1[i][j] = floatx4{0.f, 0.f, 0.f, 0.f};
            const short* Wbase = W1f + (long)mc * 12 * 8 * 512;
            short8 a0 = *(const short8*)(Wbase + (2 * wid) * 512 + lane * 8);
            short8 a1 = *(const short8*)(Wbase + (2 * wid + 1) * 512 + lane * 8);
            for (int kc = 0; kc < 12; kc++) {
                short8 ac0 = a0, ac1 = a1;
                if (kc < 11) {
                    a0 = *(const short8*)(Wbase + ((kc + 1) * 8 + 2 * wid) * 512 + lane * 8);
                    a1 = *(const short8*)(Wbase + ((kc + 1) * 8 + 2 * wid + 1) * 512 + lane * 8);
                }
                short8 bf[4];
                #pragma unroll
                for (int j = 0; j < 4; j++)
                    bf[j] = *(short8*)(xs + kc * 2048 + j * 512 + lane * 8);
                #pragma unroll
                for (int j = 0; j < 4; j++) {
                    acc1[0][j] = __builtin_amdgcn_mfma_f32_16x16x32_bf16(ac0, bf[j], acc1[0][j], 0, 0, 0);
                    acc1[1][j] = __builtin_amdgcn_mfma_f32_16x16x32_bf16(ac1, bf[j], acc1[1][j], 0, 0, 0);
                }
            }
            // ---- h-chunk -> LDS (bias + relu + bf16, phase-2 B-fragment order) ----
            __syncthreads();   // previous phase-2 readers done
            #pragma unroll
            for (int i2 = 0; i2 < 2; i2++) {
                const int mloc = wid * 32 + 16 * i2 + 4 * q;
                const int q2 = (2 * i2 + (q >> 1)) & 3;
                float bw[4];
                #pragma unroll
                for (int rr = 0; rr < 4; rr++) bw[rr] = B1p[mc * 128 + mloc + rr];
                #pragma unroll
                for (int j = 0; j < 4; j++) {
                    short pk[4];
                    #pragma unroll
                    for (int rr = 0; rr < 4; rr++) {
                        float vv = acc1[i2][j][rr] + bw[rr];
                        pk[rr] = f2bf(fmaxf(vv, 0.f));
                    }
                    *(unsigned long long*)(hs + wid * 2048 + j * 512 +
                        ((q2 << 4) | l15) * 8 + 4 * (q & 1)) = *(unsigned long long*)pk;
                }
            }
            __syncthreads();
            // ---- phase 2: accumulate into acc2 ----
            #pragma unroll
            for (int kc2 = 0; kc2 < 4; kc2++) {
                short8 bf[4];
                #pragma unroll
                for (int j = 0; j < 4; j++)
                    bf[j] = *(short8*)(hs + kc2 * 2048 + j * 512 + lane * 8);
                #pragma unroll
                for (int j = 0; j < 4; j++) {
                    acc2[0][j] = __builtin_amdgcn_mfma_f32_16x16x32_bf16(a2[kc2][0], bf[j], acc2[0][j], 0, 0, 0);
                    acc2[1][j] = __builtin_amdgcn_mfma_f32_16x16x32_bf16(a2[kc2][1], bf[j], acc2[1][j], 0, 0, 0);
                }
            }
        }
    }

    // ---- epilogue: feat fp32 ----
    {
        float* fbp = feat + (long)b * 128 * N;
        #pragma unroll
        for (int i2 = 0; i2 < 2; i2++)
            #pragma unroll
            for (int rr = 0; rr < 4; rr++) {
                int row = wid * 32 + 16 * i2 + 4 * q + rr;
                float bv = fb2[row];
                #pragma unroll
                for (int j = 0; j < 4; j++)
                    fbp[(long)row * N + n0 + 16 * j + l15] = acc2a[i2][j][rr] + bv;
            }
    }
    // ---- epilogue: E = exp bf16 rows [65][N] + pu row-sum partials ----
    __syncthreads();                 // hs reusable
    float* puld = (float*)hs;
    #pragma unroll
    for (int i2 = 0; i2 < 2; i2++)
        #pragma unroll
        for (int rr = 0; rr < 4; rr++) {
            int row = wid * 32 + 16 * i2 + 4 * q + rr;
            bool valid = row < 65;
            float bv = B2bp[row];
            float s = 0.f;
            #pragma unroll
            for (int j = 0; j < 4; j++) {
                float e = expf(acc2b[i2][j][rr] + bv);
                if (valid) {
                    Eg[((long)b * 65 + row) * N + n0 + 16 * j + l15] = f2bf(e);
                    s += e;
                }
            }
            s += __shfl_xor(s, 1); s += __shfl_xor(s, 2);
            s += __shfl_xor(s, 4); s += __shfl_xor(s, 8);
            if (valid && l15 == 0) puld[row] = s;
        }
    __syncthreads();
    if (tid < 65)
        pu[((long)b * gridDim.x + blockIdx.x) * 65 + tid] = puld[tid];
}

// ---------------- u-reduce: eu[k] = (1/65) / sum_chunks pu ----------------
__global__ void u_reduce(const float* __restrict__ pu, float* __restrict__ eu, int nch)
{
    int b = blockIdx.x, t = threadIdx.x;
    if (t >= 65) return;
    float s = 0.f;
    for (int ch = 0; ch < nch; ch++) s += pu[((long)b * nch + ch) * 65 + t];
    eu[b * 65 + t] = (1.0f / 65.0f) / s;
}

// ---------------- fused v-step + next u-partials (LDS-resident E tile) ----------------
__global__ __launch_bounds__(256) void sk_step(const short* __restrict__ Eg,
        const float* __restrict__ eu, float* __restrict__ pu, int N, float invN)
{
    __shared__ short Es[65 * 264];
    __shared__ float evs[256];
    __shared__ float eus[65];
    const int t = threadIdx.x;
    const int chunk = blockIdx.x, b = blockIdx.y;
    const int n0 = chunk * 256;
    const short* Eb = Eg + (long)b * 65 * N;
    if (t < 65) eus[t] = eu[b * 65 + t];
    #pragma unroll 4
    for (int k = 0; k < 65; k++) Es[k * 264 + t] = Eb[(long)k * N + n0 + t];
    __syncthreads();
    float sv = 0.f;
    #pragma unroll 4
    for (int k = 0; k < 65; k++) sv += bf2f(Es[k * 264 + t]) * eus[k];
    evs[t] = invN / sv;
    __syncthreads();
    const int wid = t >> 6, lane = t & 63;
    for (int k = wid; k < 65; k += 4) {
        const short* er = Es + k * 264 + lane * 4;
        float4 v4 = *(const float4*)&evs[lane * 4];
        float s = bf2f(er[0]) * v4.x + bf2f(er[1]) * v4.y + bf2f(er[2]) * v4.z + bf2f(er[3]) * v4.w;
        #pragma unroll
        for (int off = 32; off >= 1; off >>= 1) s += __shfl_xor(s, off);
        if (lane == 0) pu[((long)b * gridDim.x + chunk) * 65 + k] = s;
    }
}

// ---------------- final v-step + P + desc partials ----------------
__global__ __launch_bounds__(256) void sk_desc(const short* __restrict__ Eg,
        const float* __restrict__ eu, const float* __restrict__ feat,
        float* __restrict__ part, int N, float invN)
{
    __shared__ short Es[65 * 264];
    __shared__ float fs[128 * 33];
    __shared__ float eus[65];
    const int t = threadIdx.x;
    const int chunk = blockIdx.x, b = blockIdx.y, nch = gridDim.x;
    const int n0 = chunk * 256;
    const short* Eb = Eg + (long)b * 65 * N;
    if (t < 65) eus[t] = eu[b * 65 + t];
    #pragma unroll 4
    for (int k = 0; k < 65; k++) Es[k * 264 + t] = Eb[(long)k * N + n0 + t];
    __syncthreads();
    float sv = 0.f;
    #pragma unroll 4
    for (int k = 0; k < 65; k++) sv += bf2f(Es[k * 264 + t]) * eus[k];
    float evt = invN / sv;
    #pragma unroll 4
    for (int k = 0; k < 64; k++)
        Es[k * 264 + t] = f2bf(bf2f(Es[k * 264 + t]) * eus[k] * evt);
    __syncthreads();
    const int wid = t >> 6, lane = t & 63;
    float* pb = part + ((long)b * nch + chunk) * 8256;
    for (int k = wid; k < 64; k += 4) {
        const short* er = Es + k * 264 + lane * 4;
        float s = bf2f(er[0]) + bf2f(er[1]) + bf2f(er[2]) + bf2f(er[3]);
        #pragma unroll
        for (int off = 32; off >= 1; off >>= 1) s += __shfl_xor(s, off);
        if (lane == 0) pb[8192 + k] = s;
    }
    const int cq = t & 31, kq = t >> 5;
    float a[4][8];
    #pragma unroll
    for (int i = 0; i < 4; i++)
        #pragma unroll
        for (int j = 0; j < 8; j++) a[i][j] = 0.f;
    const float* fb = feat + (long)b * 128 * N;
    for (int ns = 0; ns < 256; ns += 32) {
        __syncthreads();
        {
            int np = t & 31, cg = t >> 5;
            #pragma unroll
            for (int ii = 0; ii < 16; ii++) {
                int c = cg * 16 + ii;
                fs[c * 33 + np] = fb[(long)c * N + n0 + ns + np];
            }
        }
        __syncthreads();
        for (int np = 0; np < 32; np++) {
            float pv[8];
            #pragma unroll
            for (int j = 0; j < 8; j++) pv[j] = bf2f(Es[(8 * kq + j) * 264 + ns + np]);
            #pragma unroll
            for (int i = 0; i < 4; i++) {
                float fv = fs[(cq + 32 * i) * 33 + np];
                #pragma unroll
                for (int j = 0; j < 8; j++) a[i][j] += fv * pv[j];
            }
        }
    }
    #pragma unroll
    for (int i = 0; i < 4; i++)
        #pragma unroll
        for (int j = 0; j < 8; j++)
            pb[(cq + 32 * i) * 64 + 8 * kq + j] = a[i][j];
}

// ---------------- desc reduce ----------------
__global__ __launch_bounds__(256) void desc_reduce(const float* __restrict__ part,
                                                   float* __restrict__ desc,
                                                   int nch, int b0, int add)
{
    __shared__ float cn[64];
    const int tid = threadIdx.x;
    const int b = blockIdx.x;
    const int cq = tid & 31, kq = tid >> 5;
    const float* pb = part + (long)b * nch * 8256;
    float a[4][8]; float rs[8];
    #pragma unroll
    for (int i = 0; i < 4; i++)
        #pragma unroll
        for (int j = 0; j < 8; j++) a[i][j] = 0.f;
    #pragma unroll
    for (int j = 0; j < 8; j++) rs[j] = 0.f;
    for (int ch = 0; ch < nch; ch++) {
        const float* p = pb + (long)ch * 8256;
        #pragma unroll
        for (int i = 0; i < 4; i++)
            #pragma unroll
            for (int j = 0; j < 8; j++) a[i][j] += p[(cq + 32 * i) * 64 + 8 * kq + j];
        #pragma unroll
        for (int j = 0; j < 8; j++) rs[j] += p[8192 + 8 * kq + j];
    }
    float sq[8];
    #pragma unroll
    for (int j = 0; j < 8; j++) {
        float inv = 1.0f / (rs[j] + 1e-8f);
        float s = 0.f;
        #pragma unroll
        for (int i = 0; i < 4; i++) { a[i][j] *= inv; s += a[i][j] * a[i][j]; }
        sq[j] = s;
    }
    #pragma unroll
    for (int off = 16; off >= 1; off >>= 1)
        #pragma unroll
        for (int j = 0; j < 8; j++) sq[j] += __shfl_xor(sq[j], off);
    if (cq == 0) {
        #pragma unroll
        for (int j = 0; j < 8; j++) cn[8 * kq + j] = sq[j];
    }
    __syncthreads();
    float* d = desc + (long)(b0 + b) * 8192;
    #pragma unroll
    for (int j = 0; j < 8; j++) {
        float inv = 1.0f / fmaxf(sqrtf(cn[8 * kq + j]), 1e-12f);
        #pragma unroll
        for (int i = 0; i < 4; i++) {
            int idx = (cq + 32 * i) * 64 + 8 * kq + j;
            float val = a[i][j] * inv;
            if (add) d[idx] += val; else d[idx] = val;
        }
    }
}

// ---------------- final ----------------
__global__ __launch_bounds__(256) void final_kernel(const float* __restrict__ desc, float* __restrict__ out)
{
    __shared__ float red[4];
    const int b = blockIdx.x;
    const float* d = desc + (long)b * 8192;
    float s = 0;
    for (int i = threadIdx.x; i < 8192; i += 256) { float t = d[i] * 0.5f; s += t * t; }
    const int wave = threadIdx.x >> 6, lane = threadIdx.x & 63;
    #pragma unroll
    for (int off = 32; off >= 1; off >>= 1) s += __shfl_xor(s, off);
    if (lane == 0) red[wave] = s;
    __syncthreads();
    float tot = red[0] + red[1] + red[2] + red[3];
    float inv = 1.0f / fmaxf(sqrtf(tot), 1e-12f);
    for (int i = threadIdx.x; i < 8192; i += 256) out[(long)b * 8192 + i] = d[i] * 0.5f * inv;
}

extern "C" void kernel_launch(void* const* d_in, const int* in_sizes, int n_in,
                              void* d_out, int out_size, void* d_ws, size_t ws_size,
                              hipStream_t stream)
{
    (void)in_sizes; (void)n_in; (void)out_size;
    const float* x = (const float*)d_in[0];
    const float *fw1[2], *fb1[2], *fw2[2], *fb2[2], *sw1[2], *sb1[2],
                *sw2[2], *sb2[2], *dw1[2], *db1[2], *dw2[2], *db2[2];
    for (int s = 0; s < 2; s++) {
        int o = 1 + s * 12;
        fw1[s] = (const float*)d_in[o + 0];  fb1[s] = (const float*)d_in[o + 1];
        fw2[s] = (const float*)d_in[o + 2];  fb2[s] = (const float*)d_in[o + 3];
        sw1[s] = (const float*)d_in[o + 4];  sb1[s] = (const float*)d_in[o + 5];
        sw2[s] = (const float*)d_in[o + 6];  sb2[s] = (const float*)d_in[o + 7];
        dw1[s] = (const float*)d_in[o + 8];  db1[s] = (const float*)d_in[o + 9];
        dw2[s] = (const float*)d_in[o + 10]; db2[s] = (const float*)d_in[o + 11];
    }

    const size_t fixed = ((size_t)2*442368*2 + 2*65536*2 + 2*81920*2
                        + 2*1152*4 + 2*128*4 + (size_t)16*8192*4) + (1 << 16);
    const size_t perb = (size_t)4096*384*2 + (size_t)1024*384*2
                      + (size_t)128*4096*4 + (size_t)65*4096*2
                      + (size_t)64*65*4 + 65*4 + (size_t)16*8256*4 + 4096;
    int CB = 4;
    const int cand[3] = {16, 8, 4};
    for (int ci = 0; ci < 3; ci++)
        if (fixed + (size_t)cand[ci] * perb <= ws_size) { CB = cand[ci]; break; }

    char* p = (char*)d_ws;
    auto alloc = [&](size_t bytes) -> char* {
        char* r = p; p += (bytes + 255) & ~(size_t)255; return r;
    };
    short* W1f  = (short*)alloc((size_t)2 * 442368 * 2);
    short* W2af = (short*)alloc((size_t)2 * 65536 * 2);
    short* W2bf = (short*)alloc((size_t)2 * 81920 * 2);
    float* B1p  = (float*)alloc((size_t)2 * 1152 * 4);
    float* B2bp = (float*)alloc((size_t)2 * 128 * 4);
    float* desc = (float*)alloc((size_t)16 * 8192 * 4);
    short* xT   = (short*)alloc((size_t)CB * 4096 * 384 * 2);
    short* x1T  = (short*)alloc((size_t)CB * 1024 * 384 * 2);
    float* feat = (float*)alloc((size_t)CB * 128 * 4096 * 4);
    short* Eg   = (short*)alloc((size_t)CB * 65 * 4096 * 2);
    float* pu   = (float*)alloc((size_t)CB * 64 * 65 * 4);
    float* eu   = (float*)alloc((size_t)CB * 65 * 4);
    float* part = (float*)alloc((size_t)CB * 16 * 8256 * 4);

    for (int s = 0; s < 2; s++) {
        wprep<<<2309, 256, 0, stream>>>(
            fw1[s], fb1[s], fw2[s], sw1[s], sb1[s], sw2[s], sb2[s],
            dw1[s], db1[s], dw2[s], db2[s],
            W1f + (size_t)s * 442368, W2af + (size_t)s * 65536,
            W2bf + (size_t)s * 81920, B1p + (size_t)s * 1152, B2bp + (size_t)s * 128);
    }

    for (int b0 = 0; b0 < 16; b0 += CB) {
        xprep<<<dim3(32, 6, CB), 256, 0, stream>>>(x + (size_t)b0 * 384 * 4096, xT, x1T);
        for (int s = 0; s < 2; s++) {
            const int N = (s == 0) ? 4096 : 1024;
            const int nch256 = N / 256;
            const float invN = 1.0f / (float)N;
            const short* xTs = (s == 0) ? xT : x1T;
            fused_mlp<<<dim3(N / 64, CB), 256, 0, stream>>>(
                W1f + (size_t)s * 442368, B1p + (size_t)s * 1152,
                W2af + (size_t)s * 65536, fb2[s],
                W2bf + (size_t)s * 81920, B2bp + (size_t)s * 128,
                xTs, feat, Eg, pu, N);
            u_reduce<<<CB, 128, 0, stream>>>(pu, eu, N / 64);                    // eu1
            sk_step<<<dim3(nch256, CB), 256, 0, stream>>>(Eg, eu, pu, N, invN);  // v1 + pu2
            u_reduce<<<CB, 128, 0, stream>>>(pu, eu, nch256);                    // eu2
            sk_step<<<dim3(nch256, CB), 256, 0, stream>>>(Eg, eu, pu, N, invN);  // v2 + pu3
            u_reduce<<<CB, 128, 0, stream>>>(pu, eu, nch256);                    // eu3
            sk_desc<<<dim3(nch256, CB), 256, 0, stream>>>(Eg, eu, feat, part, N, invN);
            desc_reduce<<<CB, 256, 0, stream>>>(part, desc, nch256, b0, s);
        }
    }
    final_kernel<<<16, 256, 0, stream>>>(desc, (float*)d_out);
}

// Round 5
// 593.474 us; speedup vs baseline: 5.0506x; 1.0230x over previous
//
#include <hip/hip_runtime.h>
#include <math.h>

typedef __attribute__((ext_vector_type(8))) short short8;
typedef __attribute__((ext_vector_type(4))) float floatx4;

__device__ inline float bf2f(short s) {
    union { unsigned u; float f; } x; x.u = ((unsigned)(unsigned short)s) << 16; return x.f;
}
__device__ inline short f2bf(float f) {
    union { float f; unsigned u; } x; x.f = f;
    unsigned r = x.u + 0x7fff + ((x.u >> 16) & 1);
    return (short)(r >> 16);
}

// ---------------- weight prep ----------------
// W1f: [c 0..4][kc 0..11][g 0..15][lane][8]  m=c*256+g*16+(l&15) (0 if >=1152), k=kc*32+(l>>4)*8+e
// W2af: [ka 0..15][g 0..7][lane][8]  r=g*16+(l&15), k=ka*32+(l>>4)*8+e  (fw2 [128x512])
// W2bf: [kb 0..19][g 0..7][lane][8]  sw2 (r<64,k<512) / dw2 (r==64,k>=512) / 0
__global__ __launch_bounds__(256) void wprep(
    const float* __restrict__ fw1, const float* __restrict__ fb1,
    const float* __restrict__ fw2,
    const float* __restrict__ sw1, const float* __restrict__ sb1,
    const float* __restrict__ sw2, const float* __restrict__ sb2,
    const float* __restrict__ dw1, const float* __restrict__ db1,
    const float* __restrict__ dw2, const float* __restrict__ db2,
    short* __restrict__ W1f, short* __restrict__ W2af, short* __restrict__ W2bf,
    float* __restrict__ B1p, float* __restrict__ B2bp)
{
    int id = blockIdx.x * 256 + threadIdx.x;
    if (id < 491520) {
        int e = id & 7, l = (id >> 3) & 63, g = (id >> 9) & 15, rest = id >> 13;
        int kc = rest % 12, c = rest / 12;
        int m = c * 256 + g * 16 + (l & 15);
        int k = kc * 32 + (l >> 4) * 8 + e;
        float v = 0.f;
        if (m < 512) v = fw1[m * 384 + k];
        else if (m < 1024) v = sw1[(m - 512) * 384 + k];
        else if (m < 1152) v = dw1[(m - 1024) * 384 + k];
        W1f[id] = f2bf(v);
        return;
    }
    id -= 491520;
    if (id < 65536) {
        int e = id & 7, l = (id >> 3) & 63, g = (id >> 9) & 7, ka = id >> 12;
        int r = g * 16 + (l & 15), k = ka * 32 + (l >> 4) * 8 + e;
        W2af[id] = f2bf(fw2[r * 512 + k]);
        return;
    }
    id -= 65536;
    if (id < 81920) {
        int e = id & 7, l = (id >> 3) & 63, g = (id >> 9) & 7, kb = id >> 12;
        int r = g * 16 + (l & 15), k = kb * 32 + (l >> 4) * 8 + e;
        float v = 0.f;
        if (r < 64 && k < 512) v = sw2[r * 512 + k];
        else if (r == 64 && k >= 512) v = dw2[k - 512];
        W2bf[id] = f2bf(v);
        return;
    }
    id -= 81920;
    if (id < 1152) {
        B1p[id] = id < 512 ? fb1[id] : id < 1024 ? sb1[id - 512] : db1[id - 1024];
        return;
    }
    id -= 1152;
    if (id < 128) B2bp[id] = id < 64 ? sb2[id] : id == 64 ? db2[0] : 0.f;
}

// ---------------- xprep ----------------
__global__ __launch_bounds__(256) void xprep(const float* __restrict__ x,
                                             short* __restrict__ xT, short* __restrict__ x1T)
{
    __shared__ float xt[64 * 129];
    const int ip = blockIdx.x;
    const int cg = blockIdx.y;
    const int b  = blockIdx.z;
    const int t  = threadIdx.x;
    #pragma unroll
    for (int u = 0; u < 32; u++) {
        int idx = t + 256 * u;
        int c = idx >> 7, sp = idx & 127;
        xt[c * 129 + sp] = x[(((long)b * 384 + cg * 64 + c) * 64 + ip * 2 + (sp >> 6)) * 64 + (sp & 63)];
    }
    __syncthreads();
    {
        int sp = t >> 1, ch = t & 1;
        short tmp[32];
        #pragma unroll
        for (int cc = 0; cc < 32; cc++) tmp[cc] = f2bf(xt[(ch * 32 + cc) * 129 + sp]);
        short* dst = xT + ((long)b * 4096 + ip * 128 + sp) * 384 + cg * 64 + ch * 32;
        #pragma unroll
        for (int v = 0; v < 4; v++) *(short8*)(dst + v * 8) = *(short8*)(tmp + v * 8);
    }
    {
        int j1 = t >> 3, c8 = t & 7;
        short tmp[8];
        #pragma unroll
        for (int e = 0; e < 8; e++) {
            int c = c8 * 8 + e;
            float v = 0.25f * (xt[c * 129 + j1 * 2]      + xt[c * 129 + j1 * 2 + 1] +
                               xt[c * 129 + 64 + j1 * 2] + xt[c * 129 + 64 + j1 * 2 + 1]);
            tmp[e] = f2bf(v);
        }
        *(short8*)(x1T + ((long)b * 1024 + ip * 32 + j1) * 384 + cg * 64 + c8 * 8) = *(short8*)tmp;
    }
}

// ---------------- fused MLP v2 ----------------
// n-tile 64, m-chunks {256,256,256,256,128}; phase1 wave-tile 64m x 64n.
// phase2: waves 0/1 -> feat (k chunks 0-1), waves 2/3 -> E (k chunks 2-4; wave3 rows 64..79).
__global__ __launch_bounds__(256, 2) void fused_mlp(
    const short* __restrict__ W1f, const float* __restrict__ B1p,
    const short* __restrict__ W2af, const float* __restrict__ fb2,
    const short* __restrict__ W2bf, const float* __restrict__ B2bp,
    const short* __restrict__ XT, float* __restrict__ feat,
    short* __restrict__ Eg, float* __restrict__ pu, int N)
{
    __shared__ short xs[12 * 2048];   // 48 KB
    __shared__ short hs[8 * 2048];    // 32 KB (256 k-rows in B-fragment order)
    const int tid = threadIdx.x;
    const int wid = tid >> 6, lane = tid & 63;
    const int l15 = lane & 15, q = lane >> 4;
    const int n0 = blockIdx.x * 64, b = blockIdx.y;

    // stage x tile [64 n x 384 k]
    {
        const int n = tid >> 2;
        const int c0 = (tid & 3) * 12;
        const short* src = XT + ((long)b * N + n0 + n) * 384 + c0 * 8;
        const int jj = n >> 4, nl = n & 15;
        #pragma unroll
        for (int i = 0; i < 12; i++) {
            int c = c0 + i;
            int kc = c >> 2, qq = c & 3;
            *(short8*)(xs + kc * 2048 + jj * 512 + ((qq << 4) | nl) * 8) =
                *(const short8*)(src + i * 8);
        }
    }
    __syncthreads();

    const int half_owner = wid >> 1;          // 0 = feat, 1 = E
    const int g0 = (wid & 1) * 4;
    const int ng = (wid == 3) ? 1 : 4;
    const short* W2f = half_owner ? W2bf : W2af;

    floatx4 acc2[4][4];
    #pragma unroll
    for (int i = 0; i < 4; i++)
        #pragma unroll
        for (int j = 0; j < 4; j++) acc2[i][j] = floatx4{0.f, 0.f, 0.f, 0.f};

    for (int c = 0; c < 5; c++) {
        const bool act1 = (c < 4) || (wid < 2);
        floatx4 acc1[4][4];
        #pragma unroll
        for (int i = 0; i < 4; i++)
            #pragma unroll
            for (int j = 0; j < 4; j++) acc1[i][j] = floatx4{0.f, 0.f, 0.f, 0.f};
        // phase1: h rows c*256 + wid*64 .. +63
        if (act1) {
            const short* Wb = W1f + (long)c * 98304;
            for (int kc = 0; kc < 12; kc++) {
                short8 a[4], bfr[4];
                #pragma unroll
                for (int i = 0; i < 4; i++)
                    a[i] = *(const short8*)(Wb + (kc * 16 + wid * 4 + i) * 512 + lane * 8);
                #pragma unroll
                for (int j = 0; j < 4; j++)
                    bfr[j] = *(short8*)(xs + kc * 2048 + j * 512 + lane * 8);
                #pragma unroll
                for (int i = 0; i < 4; i++)
                    #pragma unroll
                    for (int j = 0; j < 4; j++)
                        acc1[i][j] = __builtin_amdgcn_mfma_f32_16x16x32_bf16(a[i], bfr[j], acc1[i][j], 0, 0, 0);
            }
        }
        // phase2 for previous chunk (reads hs written last iteration)
        if (c > 0) {
            const int pc = c - 1;
            if (half_owner == (pc >= 2 ? 1 : 0)) {
                const int kb0 = (pc >= 2) ? (pc - 2) * 8 : pc * 8;
                for (int kc2 = 0; kc2 < 8; kc2++) {
                    short8 a2[4], bfr[4];
                    #pragma unroll
                    for (int i = 0; i < 4; i++)
                        if (i < ng)
                            a2[i] = *(const short8*)(W2f + ((kb0 + kc2) * 8 + g0 + i) * 512 + lane * 8);
                    #pragma unroll
                    for (int j = 0; j < 4; j++)
                        bfr[j] = *(short8*)(hs + kc2 * 2048 + j * 512 + lane * 8);
                    #pragma unroll
                    for (int i = 0; i < 4; i++)
                        if (i < ng)
                            #pragma unroll
                            for (int j = 0; j < 4; j++)
                                acc2[i][j] = __builtin_amdgcn_mfma_f32_16x16x32_bf16(a2[i], bfr[j], acc2[i][j], 0, 0, 0);
                }
            }
        }
        __syncthreads();    // all hs readers done
        // write h-chunk (bias+relu+bf16) into hs, phase-2 B-fragment order
        if (act1) {
            #pragma unroll
            for (int i = 0; i < 4; i++) {
                const int kc2 = wid * 2 + (i >> 1);
                const int qf = (i & 1) * 2 + (q >> 1);
                const int e0 = 4 * (q & 1);
                const int mrow = c * 256 + wid * 64 + i * 16 + q * 4;
                float bw[4];
                #pragma unroll
                for (int rr = 0; rr < 4; rr++) bw[rr] = B1p[mrow + rr];
                #pragma unroll
                for (int j = 0; j < 4; j++) {
                    short pk[4];
                    #pragma unroll
                    for (int rr = 0; rr < 4; rr++)
                        pk[rr] = f2bf(fmaxf(acc1[i][j][rr] + bw[rr], 0.f));
                    *(unsigned long long*)(hs + kc2 * 2048 + j * 512 + ((qf << 4) | l15) * 8 + e0) =
                        *(unsigned long long*)pk;
                }
            }
        }
        __syncthreads();    // hs visible to next iteration's phase2
    }
    // final phase2: chunk 4 (E half, kb 16..19, kc2 0..3)
    if (half_owner == 1) {
        for (int kc2 = 0; kc2 < 4; kc2++) {
            short8 a2[4], bfr[4];
            #pragma unroll
            for (int i = 0; i < 4; i++)
                if (i < ng)
                    a2[i] = *(const short8*)(W2bf + ((16 + kc2) * 8 + g0 + i) * 512 + lane * 8);
            #pragma unroll
            for (int j = 0; j < 4; j++)
                bfr[j] = *(short8*)(hs + kc2 * 2048 + j * 512 + lane * 8);
            #pragma unroll
            for (int i = 0; i < 4; i++)
                if (i < ng)
                    #pragma unroll
                    for (int j = 0; j < 4; j++)
                        acc2[i][j] = __builtin_amdgcn_mfma_f32_16x16x32_bf16(a2[i], bfr[j], acc2[i][j], 0, 0, 0);
        }
    }
    // epilogue: feat (waves 0,1)
    if (half_owner == 0) {
        float* fbp = feat + (long)b * 128 * N;
        #pragma unroll
        for (int i = 0; i < 4; i++)
            #pragma unroll
            for (int rr = 0; rr < 4; rr++) {
                int row = wid * 64 + i * 16 + q * 4 + rr;
                float bv = fb2[row];
                #pragma unroll
                for (int j = 0; j < 4; j++)
                    fbp[(long)row * N + n0 + 16 * j + l15] = acc2[i][j][rr] + bv;
            }
    }
    __syncthreads();                  // hs reads done; reuse as float scratch
    float* puld = (float*)hs;
    if (half_owner == 1) {
        #pragma unroll
        for (int i = 0; i < 4; i++) {
            if (i >= ng) continue;
            #pragma unroll
            for (int rr = 0; rr < 4; rr++) {
                int row = (wid - 2) * 64 + i * 16 + q * 4 + rr;
                bool valid = row < 65;
                float bv = B2bp[row < 128 ? row : 0];
                float s = 0.f;
                #pragma unroll
                for (int j = 0; j < 4; j++) {
                    float e = expf(acc2[i][j][rr] + bv);
                    if (valid) {
                        Eg[((long)b * 65 + row) * N + n0 + 16 * j + l15] = f2bf(e);
                        s += e;
                    }
                }
                s += __shfl_xor(s, 1); s += __shfl_xor(s, 2);
                s += __shfl_xor(s, 4); s += __shfl_xor(s, 8);
                if (valid && l15 == 0) puld[row] = s;
            }
        }
    }
    __syncthreads();
    if (tid < 65)
        pu[((long)b * gridDim.x + blockIdx.x) * 65 + tid] = puld[tid];
}

// ---------------- sk_step: eu from pu_in; v-step; next u-partials ----------------
__global__ __launch_bounds__(256) void sk_step(const short* __restrict__ Eg,
        const float* __restrict__ pu_in, float* __restrict__ pu_out,
        int N, float invN, int nch_in)
{
    __shared__ short Es[65 * 264];
    __shared__ float evs[256];
    __shared__ float eus[65];
    const int t = threadIdx.x;
    const int chunk = blockIdx.x, b = blockIdx.y;
    const int n0 = chunk * 256;
    const short* Eb = Eg + (long)b * 65 * N;
    if (t < 65) {
        float s = 0.f;
        for (int ch = 0; ch < nch_in; ch++) s += pu_in[((long)b * nch_in + ch) * 65 + t];
        eus[t] = (1.0f / 65.0f) / s;
    }
    for (int it = t; it < 2080; it += 256) {
        int k = it >> 5, n8 = it & 31;
        *(short8*)(Es + k * 264 + n8 * 8) = *(const short8*)(Eb + (long)k * N + n0 + n8 * 8);
    }
    __syncthreads();
    float sv = 0.f;
    #pragma unroll 4
    for (int k = 0; k < 65; k++) sv += bf2f(Es[k * 264 + t]) * eus[k];
    evs[t] = invN / sv;
    __syncthreads();
    const int wid = t >> 6, lane = t & 63;
    for (int k = wid; k < 65; k += 4) {
        const short* er = Es + k * 264 + lane * 4;
        float4 v4 = *(const float4*)&evs[lane * 4];
        float s = bf2f(er[0]) * v4.x + bf2f(er[1]) * v4.y + bf2f(er[2]) * v4.z + bf2f(er[3]) * v4.w;
        #pragma unroll
        for (int off = 32; off >= 1; off >>= 1) s += __shfl_xor(s, off);
        if (lane == 0) pu_out[((long)b * gridDim.x + chunk) * 65 + k] = s;
    }
}

// ---------------- sk_desc: eu; final v-step; P; desc partials ----------------
__global__ __launch_bounds__(256) void sk_desc(const short* __restrict__ Eg,
        const float* __restrict__ pu_in, const float* __restrict__ feat,
        float* __restrict__ part, int N, float invN, int nch_in)
{
    __shared__ short Es[65 * 264];
    __shared__ float fs[128 * 33];
    __shared__ float eus[65];
    const int t = threadIdx.x;
    const int chunk = blockIdx.x, b = blockIdx.y, nch = gridDim.x;
    const int n0 = chunk * 256;
    const short* Eb = Eg + (long)b * 65 * N;
    if (t < 65) {
        float s = 0.f;
        for (int ch = 0; ch < nch_in; ch++) s += pu_in[((long)b * nch_in + ch) * 65 + t];
        eus[t] = (1.0f / 65.0f) / s;
    }
    for (int it = t; it < 2080; it += 256) {
        int k = it >> 5, n8 = it & 31;
        *(short8*)(Es + k * 264 + n8 * 8) = *(const short8*)(Eb + (long)k * N + n0 + n8 * 8);
    }
    __syncthreads();
    float sv = 0.f;
    #pragma unroll 4
    for (int k = 0; k < 65; k++) sv += bf2f(Es[k * 264 + t]) * eus[k];
    float evt = invN / sv;
    #pragma unroll 4
    for (int k = 0; k < 64; k++)
        Es[k * 264 + t] = f2bf(bf2f(Es[k * 264 + t]) * eus[k] * evt);
    __syncthreads();
    const int wid = t >> 6, lane = t & 63;
    float* pb = part + ((long)b * nch + chunk) * 8256;
    for (int k = wid; k < 64; k += 4) {
        const short* er = Es + k * 264 + lane * 4;
        float s = bf2f(er[0]) + bf2f(er[1]) + bf2f(er[2]) + bf2f(er[3]);
        #pragma unroll
        for (int off = 32; off >= 1; off >>= 1) s += __shfl_xor(s, off);
        if (lane == 0) pb[8192 + k] = s;
    }
    const int cq = t & 31, kq = t >> 5;
    float a[4][8];
    #pragma unroll
    for (int i = 0; i < 4; i++)
        #pragma unroll
        for (int j = 0; j < 8; j++) a[i][j] = 0.f;
    const float* fb = feat + (long)b * 128 * N;
    for (int ns = 0; ns < 256; ns += 32) {
        __syncthreads();
        {
            int np = t & 31, cg = t >> 5;
            #pragma unroll
            for (int ii = 0; ii < 16; ii++) {
                int c = cg * 16 + ii;
                fs[c * 33 + np] = fb[(long)c * N + n0 + ns + np];
            }
        }
        __syncthreads();
        for (int np = 0; np < 32; np++) {
            float pv[8];
            #pragma unroll
            for (int j = 0; j < 8; j++) pv[j] = bf2f(Es[(8 * kq + j) * 264 + ns + np]);
            #pragma unroll
            for (int i = 0; i < 4; i++) {
                float fv = fs[(cq + 32 * i) * 33 + np];
                #pragma unroll
                for (int j = 0; j < 8; j++) a[i][j] += fv * pv[j];
            }
        }
    }
    #pragma unroll
    for (int i = 0; i < 4; i++)
        #pragma unroll
        for (int j = 0; j < 8; j++)
            pb[(cq + 32 * i) * 64 + 8 * kq + j] = a[i][j];
}

// ---------------- desc reduce (split by k-group) ----------------
__global__ __launch_bounds__(256) void desc_reduce(const float* __restrict__ part,
                                                   float* __restrict__ desc,
                                                   int nch, int b0, int add)
{
    __shared__ float cred[4][8];
    const int b = blockIdx.y, kg = blockIdx.x * 16;
    const int t = threadIdx.x;
    const int c = t & 127, kh = t >> 7;         // kh 0..1 -> 8 k each
    const float* pb = part + (long)b * nch * 8256;
    float a[8], rs[8];
    #pragma unroll
    for (int j = 0; j < 8; j++) { a[j] = 0.f; rs[j] = 0.f; }
    for (int ch = 0; ch < nch; ch++) {
        const float* p = pb + (long)ch * 8256;
        #pragma unroll
        for (int j = 0; j < 8; j++) a[j] += p[c * 64 + kg + kh * 8 + j];
        #pragma unroll
        for (int j = 0; j < 8; j++) rs[j] += p[8192 + kg + kh * 8 + j];
    }
    float sq[8];
    #pragma unroll
    for (int j = 0; j < 8; j++) {
        a[j] *= 1.0f / (rs[j] + 1e-8f);
        sq[j] = a[j] * a[j];
    }
    #pragma unroll
    for (int off = 32; off >= 1; off >>= 1)
        #pragma unroll
        for (int j = 0; j < 8; j++) sq[j] += __shfl_xor(sq[j], off);
    if ((t & 63) == 0) {
        #pragma unroll
        for (int j = 0; j < 8; j++) cred[t >> 6][j] = sq[j];
    }
    __syncthreads();
    float* d = desc + (long)(b0 + b) * 8192;
    #pragma unroll
    for (int j = 0; j < 8; j++) {
        float tot = cred[kh * 2][j] + cred[kh * 2 + 1][j];
        float inv = 1.0f / fmaxf(sqrtf(tot), 1e-12f);
        int idx = c * 64 + kg + kh * 8 + j;
        float val = a[j] * inv;
        if (add) d[idx] += val; else d[idx] = val;
    }
}

// ---------------- final ----------------
__global__ __launch_bounds__(256) void final_kernel(const float* __restrict__ desc, float* __restrict__ out)
{
    __shared__ float red[4];
    const int b = blockIdx.x;
    const float* d = desc + (long)b * 8192;
    float s = 0;
    for (int i = threadIdx.x; i < 8192; i += 256) { float t = d[i] * 0.5f; s += t * t; }
    const int wave = threadIdx.x >> 6, lane = threadIdx.x & 63;
    #pragma unroll
    for (int off = 32; off >= 1; off >>= 1) s += __shfl_xor(s, off);
    if (lane == 0) red[wave] = s;
    __syncthreads();
    float tot = red[0] + red[1] + red[2] + red[3];
    float inv = 1.0f / fmaxf(sqrtf(tot), 1e-12f);
    for (int i = threadIdx.x; i < 8192; i += 256) out[(long)b * 8192 + i] = d[i] * 0.5f * inv;
}

extern "C" void kernel_launch(void* const* d_in, const int* in_sizes, int n_in,
                              void* d_out, int out_size, void* d_ws, size_t ws_size,
                              hipStream_t stream)
{
    (void)in_sizes; (void)n_in; (void)out_size;
    const float* x = (const float*)d_in[0];
    const float *fw1[2], *fb1[2], *fw2[2], *fb2[2], *sw1[2], *sb1[2],
                *sw2[2], *sb2[2], *dw1[2], *db1[2], *dw2[2], *db2[2];
    for (int s = 0; s < 2; s++) {
        int o = 1 + s * 12;
        fw1[s] = (const float*)d_in[o + 0];  fb1[s] = (const float*)d_in[o + 1];
        fw2[s] = (const float*)d_in[o + 2];  fb2[s] = (const float*)d_in[o + 3];
        sw1[s] = (const float*)d_in[o + 4];  sb1[s] = (const float*)d_in[o + 5];
        sw2[s] = (const float*)d_in[o + 6];  sb2[s] = (const float*)d_in[o + 7];
        dw1[s] = (const float*)d_in[o + 8];  db1[s] = (const float*)d_in[o + 9];
        dw2[s] = (const float*)d_in[o + 10]; db2[s] = (const float*)d_in[o + 11];
    }

    const size_t fixed = ((size_t)2*491520*2 + 2*65536*2 + 2*81920*2
                        + 2*1152*4 + 2*128*4 + (size_t)16*8192*4) + (1 << 16);
    const size_t perb = (size_t)4096*384*2 + (size_t)1024*384*2
                      + (size_t)128*4096*4 + (size_t)65*4096*2
                      + (size_t)64*65*4 + (size_t)16*65*4 + (size_t)16*8256*4 + 8192;
    int CB = 4;
    const int cand[3] = {16, 8, 4};
    for (int ci = 0; ci < 3; ci++)
        if (fixed + (size_t)cand[ci] * perb <= ws_size) { CB = cand[ci]; break; }

    char* p = (char*)d_ws;
    auto alloc = [&](size_t bytes) -> char* {
        char* r = p; p += (bytes + 255) & ~(size_t)255; return r;
    };
    short* W1f  = (short*)alloc((size_t)2 * 491520 * 2);
    short* W2af = (short*)alloc((size_t)2 * 65536 * 2);
    short* W2bf = (short*)alloc((size_t)2 * 81920 * 2);
    float* B1p  = (float*)alloc((size_t)2 * 1152 * 4);
    float* B2bp = (float*)alloc((size_t)2 * 128 * 4);
    float* desc = (float*)alloc((size_t)16 * 8192 * 4);
    short* xT   = (short*)alloc((size_t)CB * 4096 * 384 * 2);
    short* x1T  = (short*)alloc((size_t)CB * 1024 * 384 * 2);
    float* feat = (float*)alloc((size_t)CB * 128 * 4096 * 4);
    short* Eg   = (short*)alloc((size_t)CB * 65 * 4096 * 2);
    float* puA  = (float*)alloc((size_t)CB * 64 * 65 * 4);
    float* puB  = (float*)alloc((size_t)CB * 16 * 65 * 4);
    float* part = (float*)alloc((size_t)CB * 16 * 8256 * 4);

    for (int s = 0; s < 2; s++) {
        wprep<<<2502, 256, 0, stream>>>(
            fw1[s], fb1[s], fw2[s], sw1[s], sb1[s], sw2[s], sb2[s],
            dw1[s], db1[s], dw2[s], db2[s],
            W1f + (size_t)s * 491520, W2af + (size_t)s * 65536,
            W2bf + (size_t)s * 81920, B1p + (size_t)s * 1152, B2bp + (size_t)s * 128);
    }

    for (int b0 = 0; b0 < 16; b0 += CB) {
        xprep<<<dim3(32, 6, CB), 256, 0, stream>>>(x + (size_t)b0 * 384 * 4096, xT, x1T);
        for (int s = 0; s < 2; s++) {
            const int N = (s == 0) ? 4096 : 1024;
            const int nch256 = N / 256;
            const float invN = 1.0f / (float)N;
            const short* xTs = (s == 0) ? xT : x1T;
            fused_mlp<<<dim3(N / 64, CB), 256, 0, stream>>>(
                W1f + (size_t)s * 491520, B1p + (size_t)s * 1152,
                W2af + (size_t)s * 65536, fb2[s],
                W2bf + (size_t)s * 81920, B2bp + (size_t)s * 128,
                xTs, feat, Eg, puA, N);
            sk_step<<<dim3(nch256, CB), 256, 0, stream>>>(Eg, puA, puB, N, invN, N / 64);
            sk_step<<<dim3(nch256, CB), 256, 0, stream>>>(Eg, puB, puA, N, invN, nch256);
            sk_desc<<<dim3(nch256, CB), 256, 0, stream>>>(Eg, puA, feat, part, N, invN, nch256);
            desc_reduce<<<dim3(4, CB), 256, 0, stream>>>(part, desc, nch256, b0, s);
        }
    }
    final_kernel<<<16, 256, 0, stream>>>(desc, (float*)d_out);
}

// Round 6
// 512.126 us; speedup vs baseline: 5.8528x; 1.1588x over previous
//
#include <hip/hip_runtime.h>
#include <math.h>

typedef __attribute__((ext_vector_type(8))) short short8;
typedef __attribute__((ext_vector_type(4))) float floatx4;

__device__ inline float bf2f(short s) {
    union { unsigned u; float f; } x; x.u = ((unsigned)(unsigned short)s) << 16; return x.f;
}
__device__ inline short f2bf(float f) {
    union { float f; unsigned u; } x; x.f = f;
    unsigned r = x.u + 0x7fff + ((x.u >> 16) & 1);
    return (short)(r >> 16);
}

struct WSet {
    const float *fw1, *fb1, *fw2, *sw1, *sb1, *sw2, *sb2, *dw1, *db1, *dw2, *db2;
};

// ---------------- weight prep (both scales, blockIdx.y = scale) ----------------
// W1f: [c 0..4][kc 0..11][g 0..15][lane][8]; m=c*256+g*16+(l&15) (0-pad >=1152), k=kc*32+(l>>4)*8+e
// W2af: [ka 0..15][g 0..7][lane][8] from fw2 [128x512]
// W2bf: [kb 0..23][g 0..7][lane][8]; r=g*16+(l&15): sw2 (r<64,krel<512) / dw2 (r==64,512<=krel<640) / 0
// B1p: 1280 (0-pad), B2bp: 128 (0-pad)
__global__ __launch_bounds__(256) void wprep(WSet a0, WSet a1,
    short* __restrict__ W1f, short* __restrict__ W2af, short* __restrict__ W2bf,
    float* __restrict__ B1p, float* __restrict__ B2bp)
{
    const int s = blockIdx.y;
    const WSet A = s ? a1 : a0;
    W1f  += (size_t)s * 491520;
    W2af += (size_t)s * 65536;
    W2bf += (size_t)s * 98304;
    B1p  += s * 1280;
    B2bp += s * 128;
    int id = blockIdx.x * 256 + threadIdx.x;
    if (id < 491520) {
        int e = id & 7, l = (id >> 3) & 63, g = (id >> 9) & 15, rest = id >> 13;
        int kc = rest % 12, c = rest / 12;
        int m = c * 256 + g * 16 + (l & 15);
        int k = kc * 32 + (l >> 4) * 8 + e;
        float v = 0.f;
        if (m < 512) v = A.fw1[m * 384 + k];
        else if (m < 1024) v = A.sw1[(m - 512) * 384 + k];
        else if (m < 1152) v = A.dw1[(m - 1024) * 384 + k];
        W1f[id] = f2bf(v);
        return;
    }
    id -= 491520;
    if (id < 65536) {
        int e = id & 7, l = (id >> 3) & 63, g = (id >> 9) & 7, ka = id >> 12;
        int r = g * 16 + (l & 15), k = ka * 32 + (l >> 4) * 8 + e;
        W2af[id] = f2bf(A.fw2[r * 512 + k]);
        return;
    }
    id -= 65536;
    if (id < 98304) {
        int e = id & 7, l = (id >> 3) & 63, g = (id >> 9) & 7, kb = id >> 12;
        int r = g * 16 + (l & 15), krel = kb * 32 + (l >> 4) * 8 + e;
        float v = 0.f;
        if (r < 64 && krel < 512) v = A.sw2[r * 512 + krel];
        else if (r == 64 && krel >= 512 && krel < 640) v = A.dw2[krel - 512];
        W2bf[id] = f2bf(v);
        return;
    }
    id -= 98304;
    if (id < 1280) {
        float v = 0.f;
        if (id < 512) v = A.fb1[id];
        else if (id < 1024) v = A.sb1[id - 512];
        else if (id < 1152) v = A.db1[id - 1024];
        B1p[id] = v;
        return;
    }
    id -= 1280;
    if (id < 128) B2bp[id] = id < 64 ? A.sb2[id] : id == 64 ? A.db2[0] : 0.f;
}

// ---------------- xprep ----------------
__global__ __launch_bounds__(256) void xprep(const float* __restrict__ x,
                                             short* __restrict__ xT, short* __restrict__ x1T)
{
    __shared__ float xt[64 * 129];
    const int ip = blockIdx.x;
    const int cg = blockIdx.y;
    const int b  = blockIdx.z;
    const int t  = threadIdx.x;
    #pragma unroll
    for (int u = 0; u < 32; u++) {
        int idx = t + 256 * u;
        int c = idx >> 7, sp = idx & 127;
        xt[c * 129 + sp] = x[(((long)b * 384 + cg * 64 + c) * 64 + ip * 2 + (sp >> 6)) * 64 + (sp & 63)];
    }
    __syncthreads();
    {
        int sp = t >> 1, ch = t & 1;
        short tmp[32];
        #pragma unroll
        for (int cc = 0; cc < 32; cc++) tmp[cc] = f2bf(xt[(ch * 32 + cc) * 129 + sp]);
        short* dst = xT + ((long)b * 4096 + ip * 128 + sp) * 384 + cg * 64 + ch * 32;
        #pragma unroll
        for (int v = 0; v < 4; v++) *(short8*)(dst + v * 8) = *(short8*)(tmp + v * 8);
    }
    {
        int j1 = t >> 3, c8 = t & 7;
        short tmp[8];
        #pragma unroll
        for (int e = 0; e < 8; e++) {
            int c = c8 * 8 + e;
            float v = 0.25f * (xt[c * 129 + j1 * 2]      + xt[c * 129 + j1 * 2 + 1] +
                               xt[c * 129 + 64 + j1 * 2] + xt[c * 129 + 64 + j1 * 2 + 1]);
            tmp[e] = f2bf(v);
        }
        *(short8*)(x1T + ((long)b * 1024 + ip * 32 + j1) * 384 + cg * 64 + c8 * 8) = *(short8*)tmp;
    }
}

// ---------------- fused MLP v3 (both scales in one grid) ----------------
// n-tile 64; m-chunks of 256 (5); phase1 wave-tile 64m x 64n with 1-deep A prefetch.
// phase2 balanced: slots 0,1 = feat groups (2*wid, 2*wid+1); slot 2 = E group wid; slot 3 (wid0) = E group 4.
__global__ __launch_bounds__(256, 2) void fused_mlp(
    const short* __restrict__ W1f_, const float* __restrict__ B1p_,
    const short* __restrict__ W2af_, const float* __restrict__ fb2_0, const float* __restrict__ fb2_1,
    const short* __restrict__ W2bf_, const float* __restrict__ B2bp_,
    const short* __restrict__ xT, const short* __restrict__ x1T,
    float* __restrict__ feat0, float* __restrict__ feat1,
    short* __restrict__ Eg0, short* __restrict__ Eg1,
    float* __restrict__ pu0, float* __restrict__ pu1)
{
    __shared__ short xs[12 * 2048];   // 48 KB
    __shared__ short hs[8 * 2048];    // 32 KB (256 k-rows, B-fragment order)
    const int tid = threadIdx.x;
    const int wid = tid >> 6, lane = tid & 63;
    const int l15 = lane & 15, q = lane >> 4;
    const int bx = blockIdx.x, b = blockIdx.y;
    const int sc = bx >= 64;
    const int tile = sc ? bx - 64 : bx;
    const int N = sc ? 1024 : 4096;
    const int n0 = tile * 64;
    const short* XT = sc ? x1T : xT;
    const short* W1f = W1f_ + (size_t)sc * 491520;
    const float* B1p = B1p_ + sc * 1280;
    const short* W2af = W2af_ + (size_t)sc * 65536;
    const short* W2bf = W2bf_ + (size_t)sc * 98304;
    const float* fb2 = sc ? fb2_1 : fb2_0;
    const float* B2bp = B2bp_ + sc * 128;
    float* feat = (sc ? feat1 : feat0) + (long)b * 128 * N;
    short* Eg = (sc ? Eg1 : Eg0) + (long)b * 65 * N;
    float* pu = sc ? pu1 : pu0;
    const int npart = sc ? 16 : 64;

    // stage x tile [64 n x 384 k] into fragment-order LDS
    {
        const int n = tid >> 2;
        const int c0 = (tid & 3) * 12;
        const short* src = XT + ((long)b * N + n0 + n) * 384 + c0 * 8;
        const int jj = n >> 4, nl = n & 15;
        #pragma unroll
        for (int i = 0; i < 12; i++) {
            int c = c0 + i;
            int kc = c >> 2, qq = c & 3;
            *(short8*)(xs + kc * 2048 + jj * 512 + ((qq << 4) | nl) * 8) =
                *(const short8*)(src + i * 8);
        }
    }
    __syncthreads();

    floatx4 acc2[4][4];
    #pragma unroll
    for (int i = 0; i < 4; i++)
        #pragma unroll
        for (int j = 0; j < 4; j++) acc2[i][j] = floatx4{0.f, 0.f, 0.f, 0.f};

    auto phase2 = [&](int pc) {
        if (pc < 2) {
            for (int kc2 = 0; kc2 < 8; kc2++) {
                short8 bfr[4];
                #pragma unroll
                for (int j = 0; j < 4; j++)
                    bfr[j] = *(short8*)(hs + kc2 * 2048 + j * 512 + lane * 8);
                short8 aA = *(const short8*)(W2af + ((pc * 8 + kc2) * 8 + 2 * wid) * 512 + lane * 8);
                short8 aB = *(const short8*)(W2af + ((pc * 8 + kc2) * 8 + 2 * wid + 1) * 512 + lane * 8);
                #pragma unroll
                for (int j = 0; j < 4; j++) {
                    acc2[0][j] = __builtin_amdgcn_mfma_f32_16x16x32_bf16(aA, bfr[j], acc2[0][j], 0, 0, 0);
                    acc2[1][j] = __builtin_amdgcn_mfma_f32_16x16x32_bf16(aB, bfr[j], acc2[1][j], 0, 0, 0);
                }
            }
        } else {
            for (int kc2 = 0; kc2 < 8; kc2++) {
                short8 bfr[4];
                #pragma unroll
                for (int j = 0; j < 4; j++)
                    bfr[j] = *(short8*)(hs + kc2 * 2048 + j * 512 + lane * 8);
                short8 aC = *(const short8*)(W2bf + (((pc - 2) * 8 + kc2) * 8 + wid) * 512 + lane * 8);
                #pragma unroll
                for (int j = 0; j < 4; j++)
                    acc2[2][j] = __builtin_amdgcn_mfma_f32_16x16x32_bf16(aC, bfr[j], acc2[2][j], 0, 0, 0);
                if (wid == 0) {
                    short8 aD = *(const short8*)(W2bf + (((pc - 2) * 8 + kc2) * 8 + 4) * 512 + lane * 8);
                    #pragma unroll
                    for (int j = 0; j < 4; j++)
                        acc2[3][j] = __builtin_amdgcn_mfma_f32_16x16x32_bf16(aD, bfr[j], acc2[3][j], 0, 0, 0);
                }
            }
        }
    };

    for (int c = 0; c < 5; c++) {
        // phase1: h rows c*256 + wid*64 .. +63, with 1-deep A prefetch
        floatx4 acc1[4][4];
        #pragma unroll
        for (int i = 0; i < 4; i++)
            #pragma unroll
            for (int j = 0; j < 4; j++) acc1[i][j] = floatx4{0.f, 0.f, 0.f, 0.f};
        const short* Wb = W1f + (long)c * 98304;
        short8 an[4];
        #pragma unroll
        for (int i = 0; i < 4; i++)
            an[i] = *(const short8*)(Wb + (wid * 4 + i) * 512 + lane * 8);
        for (int kc = 0; kc < 12; kc++) {
            short8 ac[4];
            #pragma unroll
            for (int i = 0; i < 4; i++) ac[i] = an[i];
            if (kc < 11) {
                #pragma unroll
                for (int i = 0; i < 4; i++)
                    an[i] = *(const short8*)(Wb + ((kc + 1) * 16 + wid * 4 + i) * 512 + lane * 8);
            }
            short8 bfr[4];
            #pragma unroll
            for (int j = 0; j < 4; j++)
                bfr[j] = *(short8*)(xs + kc * 2048 + j * 512 + lane * 8);
            #pragma unroll
            for (int i = 0; i < 4; i++)
                #pragma unroll
                for (int j = 0; j < 4; j++)
                    acc1[i][j] = __builtin_amdgcn_mfma_f32_16x16x32_bf16(ac[i], bfr[j], acc1[i][j], 0, 0, 0);
        }
        if (c > 0) phase2(c - 1);
        __syncthreads();   // hs readers done
        // h-chunk -> hs (bias + relu + bf16), phase-2 B-fragment order
        #pragma unroll
        for (int i = 0; i < 4; i++) {
            const int kc2 = wid * 2 + (i >> 1);
            const int qf = (i & 1) * 2 + (q >> 1);
            const int e0 = 4 * (q & 1);
            const int mrow = c * 256 + wid * 64 + i * 16 + q * 4;
            float bw[4];
            #pragma unroll
            for (int rr = 0; rr < 4; rr++) bw[rr] = B1p[mrow + rr];
            #pragma unroll
            for (int j = 0; j < 4; j++) {
                short pk[4];
                #pragma unroll
                for (int rr = 0; rr < 4; rr++)
                    pk[rr] = f2bf(fmaxf(acc1[i][j][rr] + bw[rr], 0.f));
                *(unsigned long long*)(hs + kc2 * 2048 + j * 512 + ((qf << 4) | l15) * 8 + e0) =
                    *(unsigned long long*)pk;
            }
        }
        __syncthreads();   // hs visible
    }
    phase2(4);

    // epilogue: feat (slots 0,1)
    #pragma unroll
    for (int slot = 0; slot < 2; slot++) {
        int row0 = (2 * wid + slot) * 16 + q * 4;
        #pragma unroll
        for (int rr = 0; rr < 4; rr++) {
            float bv = fb2[row0 + rr];
            #pragma unroll
            for (int j = 0; j < 4; j++)
                feat[(long)(row0 + rr) * N + n0 + 16 * j + l15] = acc2[slot][j][rr] + bv;
        }
    }
    __syncthreads();               // all phase2(4) hs reads done; reuse hs
    float* puld = (float*)hs;
    // E slot 2: rows wid*16 .. +15
    #pragma unroll
    for (int rr = 0; rr < 4; rr++) {
        int row = wid * 16 + q * 4 + rr;
        float bv = B2bp[row];
        float s = 0.f;
        #pragma unroll
        for (int j = 0; j < 4; j++) {
            float e = expf(acc2[2][j][rr] + bv);
            Eg[(long)row * N + n0 + 16 * j + l15] = f2bf(e);
            s += e;
        }
        s += __shfl_xor(s, 1); s += __shfl_xor(s, 2);
        s += __shfl_xor(s, 4); s += __shfl_xor(s, 8);
        if (l15 == 0) puld[row] = s;
    }
    // E slot 3 (wave 0): row 64 only
    if (wid == 0) {
        #pragma unroll
        for (int rr = 0; rr < 4; rr++) {
            int row = 64 + q * 4 + rr;
            bool valid = (row == 64);
            float bv = B2bp[64];
            float s = 0.f;
            #pragma unroll
            for (int j = 0; j < 4; j++) {
                float e = expf(acc2[3][j][rr] + bv);
                if (valid) {
                    Eg[(long)64 * N + n0 + 16 * j + l15] = f2bf(e);
                    s += e;
                }
            }
            s += __shfl_xor(s, 1); s += __shfl_xor(s, 2);
            s += __shfl_xor(s, 4); s += __shfl_xor(s, 8);
            if (valid && l15 == 0) puld[64] = s;
        }
    }
    __syncthreads();
    if (tid < 65)
        pu[((long)b * npart + tile) * 65 + tid] = puld[tid];
}

// ---------------- sk_step (both scales): eu from pin; v-step; next u-partials ----------------
__global__ __launch_bounds__(256) void sk_step(
    const short* __restrict__ Eg0, const short* __restrict__ Eg1,
    const float* __restrict__ pin0, const float* __restrict__ pin1,
    float* __restrict__ pout0, float* __restrict__ pout1, int nin0, int nin1)
{
    __shared__ short Es[65 * 264];
    __shared__ float evs[256];
    __shared__ float eus[65];
    const int t = threadIdx.x;
    const int bx = blockIdx.x, b = blockIdx.y;
    const int sc = bx >= 16;
    const int chunk = sc ? bx - 16 : bx;
    const int N = sc ? 1024 : 4096;
    const float invN = sc ? (1.0f / 1024.0f) : (1.0f / 4096.0f);
    const int n0 = chunk * 256;
    const short* Eb = (sc ? Eg1 : Eg0) + (long)b * 65 * N;
    const float* pin = sc ? pin1 : pin0;
    const int nin = sc ? nin1 : nin0;
    float* pout = sc ? pout1 : pout0;
    const int nout = sc ? 4 : 16;
    if (t < 65) {
        float s = 0.f;
        for (int ch = 0; ch < nin; ch++) s += pin[((long)b * nin + ch) * 65 + t];
        eus[t] = (1.0f / 65.0f) / s;
    }
    for (int it = t; it < 2080; it += 256) {
        int k = it >> 5, n8 = it & 31;
        *(short8*)(Es + k * 264 + n8 * 8) = *(const short8*)(Eb + (long)k * N + n0 + n8 * 8);
    }
    __syncthreads();
    float sv = 0.f;
    #pragma unroll 4
    for (int k = 0; k < 65; k++) sv += bf2f(Es[k * 264 + t]) * eus[k];
    evs[t] = invN / sv;
    __syncthreads();
    const int wid = t >> 6, lane = t & 63;
    for (int k = wid; k < 65; k += 4) {
        const short* er = Es + k * 264 + lane * 4;
        float4 v4 = *(const float4*)&evs[lane * 4];
        float s = bf2f(er[0]) * v4.x + bf2f(er[1]) * v4.y + bf2f(er[2]) * v4.z + bf2f(er[3]) * v4.w;
        #pragma unroll
        for (int off = 32; off >= 1; off >>= 1) s += __shfl_xor(s, off);
        if (lane == 0) pout[((long)b * nout + chunk) * 65 + k] = s;
    }
}

// ---------------- sk_desc (both scales): eu; final v-step; P; desc partials ----------------
__global__ __launch_bounds__(256) void sk_desc(
    const short* __restrict__ Eg0, const short* __restrict__ Eg1,
    const float* __restrict__ pin0, const float* __restrict__ pin1,
    const float* __restrict__ feat0, const float* __restrict__ feat1,
    float* __restrict__ part0, float* __restrict__ part1, int nin0, int nin1)
{
    __shared__ short Es[65 * 264];
    __shared__ float fs[128 * 33];
    __shared__ float eus[65];
    const int t = threadIdx.x;
    const int bx = blockIdx.x, b = blockIdx.y;
    const int sc = bx >= 16;
    const int chunk = sc ? bx - 16 : bx;
    const int N = sc ? 1024 : 4096;
    const float invN = sc ? (1.0f / 1024.0f) : (1.0f / 4096.0f);
    const int nch = sc ? 4 : 16;
    const int n0 = chunk * 256;
    const short* Eb = (sc ? Eg1 : Eg0) + (long)b * 65 * N;
    const float* pin = sc ? pin1 : pin0;
    const int nin = sc ? nin1 : nin0;
    const float* fb = (sc ? feat1 : feat0) + (long)b * 128 * N;
    float* part = sc ? part1 : part0;
    if (t < 65) {
        float s = 0.f;
        for (int ch = 0; ch < nin; ch++) s += pin[((long)b * nin + ch) * 65 + t];
        eus[t] = (1.0f / 65.0f) / s;
    }
    for (int it = t; it < 2080; it += 256) {
        int k = it >> 5, n8 = it & 31;
        *(short8*)(Es + k * 264 + n8 * 8) = *(const short8*)(Eb + (long)k * N + n0 + n8 * 8);
    }
    __syncthreads();
    float sv = 0.f;
    #pragma unroll 4
    for (int k = 0; k < 65; k++) sv += bf2f(Es[k * 264 + t]) * eus[k];
    float evt = invN / sv;
    #pragma unroll 4
    for (int k = 0; k < 64; k++)
        Es[k * 264 + t] = f2bf(bf2f(Es[k * 264 + t]) * eus[k] * evt);
    __syncthreads();
    const int wid = t >> 6, lane = t & 63;
    float* pb = part + ((long)b * nch + chunk) * 8256;
    for (int k = wid; k < 64; k += 4) {
        const short* er = Es + k * 264 + lane * 4;
        float s = bf2f(er[0]) + bf2f(er[1]) + bf2f(er[2]) + bf2f(er[3]);
        #pragma unroll
        for (int off = 32; off >= 1; off >>= 1) s += __shfl_xor(s, off);
        if (lane == 0) pb[8192 + k] = s;
    }
    const int cq = t & 31, kq = t >> 5;
    float a[4][8];
    #pragma unroll
    for (int i = 0; i < 4; i++)
        #pragma unroll
        for (int j = 0; j < 8; j++) a[i][j] = 0.f;
    for (int ns = 0; ns < 256; ns += 32) {
        __syncthreads();
        {
            int np = t & 31, cg = t >> 5;
            #pragma unroll
            for (int ii = 0; ii < 16; ii++) {
                int c = cg * 16 + ii;
                fs[c * 33 + np] = fb[(long)c * N + n0 + ns + np];
            }
        }
        __syncthreads();
        for (int np = 0; np < 32; np++) {
            float pv[8];
            #pragma unroll
            for (int j = 0; j < 8; j++) pv[j] = bf2f(Es[(8 * kq + j) * 264 + ns + np]);
            #pragma unroll
            for (int i = 0; i < 4; i++) {
                float fv = fs[(cq + 32 * i) * 33 + np];
                #pragma unroll
                for (int j = 0; j < 8; j++) a[i][j] += fv * pv[j];
            }
        }
    }
    #pragma unroll
    for (int i = 0; i < 4; i++)
        #pragma unroll
        for (int j = 0; j < 8; j++)
            pb[(cq + 32 * i) * 64 + 8 * kq + j] = a[i][j];
}

// ---------------- desc reduce (both scales; separate desc buffers) ----------------
__global__ __launch_bounds__(256) void desc_reduce(
    const float* __restrict__ part0, const float* __restrict__ part1,
    float* __restrict__ desc0, float* __restrict__ desc1, int b0)
{
    __shared__ float cred[4][8];
    const int bx = blockIdx.x, b = blockIdx.y;
    const int sc = bx >= 4;
    const int kg = (bx & 3) * 16;
    const int nch = sc ? 4 : 16;
    const float* pb = (sc ? part1 : part0) + (long)b * nch * 8256;
    float* desc = sc ? desc1 : desc0;
    const int t = threadIdx.x;
    const int c = t & 127, kh = t >> 7;
    float a[8], rs[8];
    #pragma unroll
    for (int j = 0; j < 8; j++) { a[j] = 0.f; rs[j] = 0.f; }
    for (int ch = 0; ch < nch; ch++) {
        const float* p = pb + (long)ch * 8256;
        #pragma unroll
        for (int j = 0; j < 8; j++) a[j] += p[c * 64 + kg + kh * 8 + j];
        #pragma unroll
        for (int j = 0; j < 8; j++) rs[j] += p[8192 + kg + kh * 8 + j];
    }
    float sq[8];
    #pragma unroll
    for (int j = 0; j < 8; j++) {
        a[j] *= 1.0f / (rs[j] + 1e-8f);
        sq[j] = a[j] * a[j];
    }
    #pragma unroll
    for (int off = 32; off >= 1; off >>= 1)
        #pragma unroll
        for (int j = 0; j < 8; j++) sq[j] += __shfl_xor(sq[j], off);
    if ((t & 63) == 0) {
        #pragma unroll
        for (int j = 0; j < 8; j++) cred[t >> 6][j] = sq[j];
    }
    __syncthreads();
    float* d = desc + (long)(b0 + b) * 8192;
    #pragma unroll
    for (int j = 0; j < 8; j++) {
        float tot = cred[kh * 2][j] + cred[kh * 2 + 1][j];
        float inv = 1.0f / fmaxf(sqrtf(tot), 1e-12f);
        d[c * 64 + kg + kh * 8 + j] = a[j] * inv;
    }
}

// ---------------- final: g = mean(desc0,desc1); normalize ----------------
__global__ __launch_bounds__(256) void final_kernel(const float* __restrict__ desc0,
                                                    const float* __restrict__ desc1,
                                                    float* __restrict__ out)
{
    __shared__ float red[4];
    const int b = blockIdx.x;
    const float* d0 = desc0 + (long)b * 8192;
    const float* d1 = desc1 + (long)b * 8192;
    float s = 0;
    for (int i = threadIdx.x; i < 8192; i += 256) {
        float t = (d0[i] + d1[i]) * 0.5f; s += t * t;
    }
    const int wave = threadIdx.x >> 6, lane = threadIdx.x & 63;
    #pragma unroll
    for (int off = 32; off >= 1; off >>= 1) s += __shfl_xor(s, off);
    if (lane == 0) red[wave] = s;
    __syncthreads();
    float tot = red[0] + red[1] + red[2] + red[3];
    float inv = 1.0f / fmaxf(sqrtf(tot), 1e-12f);
    for (int i = threadIdx.x; i < 8192; i += 256)
        out[(long)b * 8192 + i] = (d0[i] + d1[i]) * 0.5f * inv;
}

extern "C" void kernel_launch(void* const* d_in, const int* in_sizes, int n_in,
                              void* d_out, int out_size, void* d_ws, size_t ws_size,
                              hipStream_t stream)
{
    (void)in_sizes; (void)n_in; (void)out_size;
    const float* x = (const float*)d_in[0];
    WSet ws2[2];
    const float* fb2p[2];
    for (int s = 0; s < 2; s++) {
        int o = 1 + s * 12;
        ws2[s].fw1 = (const float*)d_in[o + 0];  ws2[s].fb1 = (const float*)d_in[o + 1];
        ws2[s].fw2 = (const float*)d_in[o + 2];  fb2p[s]    = (const float*)d_in[o + 3];
        ws2[s].sw1 = (const float*)d_in[o + 4];  ws2[s].sb1 = (const float*)d_in[o + 5];
        ws2[s].sw2 = (const float*)d_in[o + 6];  ws2[s].sb2 = (const float*)d_in[o + 7];
        ws2[s].dw1 = (const float*)d_in[o + 8];  ws2[s].db1 = (const float*)d_in[o + 9];
        ws2[s].dw2 = (const float*)d_in[o + 10]; ws2[s].db2 = (const float*)d_in[o + 11];
    }

    const size_t fixed = ((size_t)2*491520*2 + 2*65536*2 + 2*98304*2
                        + 2*1280*4 + 2*128*4 + (size_t)2*16*8192*4) + (1 << 16);
    const size_t perb = (size_t)4096*384*2 + (size_t)1024*384*2
                      + (size_t)128*4096*4 + (size_t)128*1024*4
                      + (size_t)65*4096*2 + (size_t)65*1024*2
                      + (size_t)(64+16)*65*4 + (size_t)(16+4)*65*4
                      + (size_t)16*8256*4 + (size_t)4*8256*4 + 8192;
    int CB = 4;
    const int cand[3] = {16, 8, 4};
    for (int ci = 0; ci < 3; ci++)
        if (fixed + (size_t)cand[ci] * perb <= ws_size) { CB = cand[ci]; break; }

    char* p = (char*)d_ws;
    auto alloc = [&](size_t bytes) -> char* {
        char* r = p; p += (bytes + 255) & ~(size_t)255; return r;
    };
    short* W1f   = (short*)alloc((size_t)2 * 491520 * 2);
    short* W2af  = (short*)alloc((size_t)2 * 65536 * 2);
    short* W2bf  = (short*)alloc((size_t)2 * 98304 * 2);
    float* B1p   = (float*)alloc((size_t)2 * 1280 * 4);
    float* B2bp  = (float*)alloc((size_t)2 * 128 * 4);
    float* desc0 = (float*)alloc((size_t)16 * 8192 * 4);
    float* desc1 = (float*)alloc((size_t)16 * 8192 * 4);
    short* xT    = (short*)alloc((size_t)CB * 4096 * 384 * 2);
    short* x1T   = (short*)alloc((size_t)CB * 1024 * 384 * 2);
    float* feat0 = (float*)alloc((size_t)CB * 128 * 4096 * 4);
    float* feat1 = (float*)alloc((size_t)CB * 128 * 1024 * 4);
    short* Eg0   = (short*)alloc((size_t)CB * 65 * 4096 * 2);
    short* Eg1   = (short*)alloc((size_t)CB * 65 * 1024 * 2);
    float* puA0  = (float*)alloc((size_t)CB * 64 * 65 * 4);
    float* puA1  = (float*)alloc((size_t)CB * 16 * 65 * 4);
    float* puB0  = (float*)alloc((size_t)CB * 16 * 65 * 4);
    float* puB1  = (float*)alloc((size_t)CB * 4 * 65 * 4);
    float* part0 = (float*)alloc((size_t)CB * 16 * 8256 * 4);
    float* part1 = (float*)alloc((size_t)CB * 4 * 8256 * 4);

    wprep<<<dim3(2566, 2), 256, 0, stream>>>(ws2[0], ws2[1], W1f, W2af, W2bf, B1p, B2bp);

    for (int b0 = 0; b0 < 16; b0 += CB) {
        xprep<<<dim3(32, 6, CB), 256, 0, stream>>>(x + (size_t)b0 * 384 * 4096, xT, x1T);
        fused_mlp<<<dim3(80, CB), 256, 0, stream>>>(
            W1f, B1p, W2af, fb2p[0], fb2p[1], W2bf, B2bp,
            xT, x1T, feat0, feat1, Eg0, Eg1, puA0, puA1);
        sk_step<<<dim3(20, CB), 256, 0, stream>>>(Eg0, Eg1, puA0, puA1, puB0, puB1, 64, 16);
        sk_step<<<dim3(20, CB), 256, 0, stream>>>(Eg0, Eg1, puB0, puB1, puA0, puA1, 16, 4);
        sk_desc<<<dim3(20, CB), 256, 0, stream>>>(Eg0, Eg1, puA0, puA1,
                                                  feat0, feat1, part0, part1, 16, 4);
        desc_reduce<<<dim3(8, CB), 256, 0, stream>>>(part0, part1, desc0, desc1, b0);
    }
    final_kernel<<<16, 256, 0, stream>>>(desc0, desc1, (float*)d_out);
}